// Round 3
// baseline (604.330 us; speedup 1.0000x reference)
//
#include <hip/hip_runtime.h>
#include <math.h>

// VariableSelectionNetwork — round 5b (compile fix: nontemporal store needs
// ext_vector_type, not HIP_vector_type float4).
// Round-4 post-mortem: 512-thr blocks still at the 256-reg cap (128 arch +
// 128 accum); x2p(32) pushed demand to ~290 -> ~70MB/side scratch traffic.
// Plus partial-line out stores -> ~64MB RFO fetch.
// Fixes:
//  * x2p dropped: gate phase RE-READS x2 from sA (it's still there after
//    GEMM2, which only reads sA). Frees 32 VGPRs -> no spills.
//  * LN partials moved to sB1 (free after GEMM2) so sA survives for re-read.
//  * Output bounced through LDS fp32 [64][512] -> contiguous f32x4
//    nontemporal stores (full-line, no RFO, no L2 pollution).
//  * Same xr-re-read fix in ctx_mfma (same reg-cap spill pattern).

#define H 512
#define NF 4
#define MTOT 32768

typedef unsigned short u16;
typedef unsigned int u32;
typedef __attribute__((ext_vector_type(8))) short short8;   // 8 bf16 = 4 VGPRs
typedef __attribute__((ext_vector_type(4))) float f32x4;    // MFMA C/D + NT stores

__device__ __forceinline__ u16 f2bf(float x) {
  union { float f; u32 u; } v; v.f = x;
  return (u16)((v.u + 0x7fffu + ((v.u >> 16) & 1u)) >> 16);  // RNE
}
__device__ __forceinline__ float bf2f(u32 h16) {
  union { u32 u; float f; } v; v.u = h16 << 16;
  return v.f;
}
__device__ __forceinline__ float elu_f(float x) {
  return x > 0.0f ? x : (__expf(x) - 1.0f);
}
__device__ __forceinline__ float sigmoid_f(float x) {
  return __builtin_amdgcn_rcpf(1.0f + __expf(-x));
}

// async global->LDS, 16B per lane; LDS dest = wave-uniform base + lane*16.
__device__ __forceinline__ void glld16(const void* g, void* l) {
  __builtin_amdgcn_global_load_lds(
      (const __attribute__((address_space(1))) u32*)(unsigned long long)(uintptr_t)g,
      (__attribute__((address_space(3))) u32*)(u32)(uintptr_t)l, 16, 0, 0);
}

#define MFMA16(a, b, c) __builtin_amdgcn_mfma_f32_16x16x32_bf16((a), (b), (c), 0, 0, 0)

// x2/x value stored by store_x2_pair at logical (m,n):
// sA[m*512 + (((n>>3)^(m&7))<<3) + (n&7)]
__device__ __forceinline__ int sA_idx(int m, int n) {
  return m * 512 + ((((n >> 3) ^ (m & 7)) << 3) + (n & 7));
}

// ---------------- pack_weights: fp32 -> bf16 B-fragment-major ----------------
// Packed per matrix: (((kk*32 + ntg)*64 + lane)*8 + j); chunk kk = 32k x 512n
// = 32KB contiguous. mats 0-3 W2[f], 4-7 Wg[f], 8 W1c, 9 W2c, 10 Wgc.
__global__ __launch_bounds__(256)
void pack_weights(const float* __restrict__ W2, const float* __restrict__ Wg,
                  const float* __restrict__ W1c, const float* __restrict__ W2c,
                  const float* __restrict__ Wgc,
                  u16* __restrict__ W2p, u16* __restrict__ Wgp, u16* __restrict__ Cp) {
  int g = blockIdx.x * 256 + threadIdx.x;       // 0 .. 11*32768-1
  int r = g & 32767; int mat = g >> 15;
  if (mat >= 11) return;
  int lane = r & 63, nt = (r >> 6) & 31, kk = (r >> 11) & 15;
  const float* src; u16* dst;
  if (mat < 4)      { src = W2 + (size_t)mat * 262144;       dst = W2p + (size_t)mat * 262144; }
  else if (mat < 8) { src = Wg + (size_t)(mat - 4) * 262144; dst = Wgp + (size_t)(mat - 4) * 262144; }
  else              { src = (mat == 8 ? W1c : (mat == 9 ? W2c : Wgc));
                      dst = Cp + (size_t)(mat - 8) * 262144; }
  dst += (((size_t)kk * 32 + nt) * 64 + lane) * 8;
  int n  = nt * 16 + (lane & 15);
  int k0 = kk * 32 + (lane >> 4) * 8;
  short8 pk;
  #pragma unroll
  for (int j = 0; j < 8; ++j) pk[j] = (short)f2bf(src[(size_t)(k0 + j) * H + n]);
  *(short8*)dst = pk;
}

struct TileCtx {
  int tid, wid, lane, quad, col;
};

// ======================= 16-wave machinery (ctx_mfma) =======================
// Block: 1024 thr = 16 waves. M-tile 64 rows. Wave wid owns cols wid*32..+31
// (nt=2 of 16). Per-thread frags: mt=4, nt=2. sA: 64KB bf16 [m][k] XOR-swizzled
// (16B groups, grp = (k>>3) ^ (m&7)). sB: 2 x 32KB chunk buffers (BK=32).

template <bool PREFETCH_TAIL>
__device__ __forceinline__ void gemm_kloop(const TileCtx& c, const u16* Wp,
                                           const u16* nextWp,
                                           u16* sA, u16* sB0, u16* sB1,
                                           f32x4 acc[4][2]) {
  #pragma unroll 1
  for (int kk = 0; kk < 16; ++kk) {
    if (kk < 15) {
      const u16* src = Wp + (kk + 1) * 16384 + c.tid * 8;
      u16* dst = (((kk + 1) & 1) ? sB1 : sB0) + c.tid * 8;
      glld16(src, dst);
      glld16(src + 8192, dst + 8192);
    } else if (PREFETCH_TAIL) {
      const u16* src = nextWp + c.tid * 8;
      glld16(src, sB0 + c.tid * 8);
      glld16(src + 8192, sB0 + c.tid * 8 + 8192);
    }
    const u16* bp = ((kk & 1) ? sB1 : sB0) + c.wid * 1024 + c.lane * 8;
    short8 bb0 = *(const short8*)(bp);
    short8 bb1 = *(const short8*)(bp + 512);
    const int kq = kk * 4 + c.quad;
    const int s0 = (kq ^ (c.col & 7)) * 8;
    short8 a0 = *(const short8*)&sA[(     c.col) * 512 + s0];
    short8 a1 = *(const short8*)&sA[(16 + c.col) * 512 + s0];
    short8 a2 = *(const short8*)&sA[(32 + c.col) * 512 + s0];
    short8 a3 = *(const short8*)&sA[(48 + c.col) * 512 + s0];
    acc[0][0] = MFMA16(a0, bb0, acc[0][0]); acc[0][1] = MFMA16(a0, bb1, acc[0][1]);
    acc[1][0] = MFMA16(a1, bb0, acc[1][0]); acc[1][1] = MFMA16(a1, bb1, acc[1][1]);
    acc[2][0] = MFMA16(a2, bb0, acc[2][0]); acc[2][1] = MFMA16(a2, bb1, acc[2][1]);
    acc[3][0] = MFMA16(a3, bb0, acc[3][0]); acc[3][1] = MFMA16(a3, bb1, acc[3][1]);
    __syncthreads();
  }
}

__device__ __forceinline__ void store_x2_pair(const TileCtx& c, u16* sA,
                                              int mt, int nt, u32 o01, u32 o23) {
  const bool even = (c.lane & 1) == 0;
  const u32 send = even ? o23 : o01;
  const u32 recv = (u32)__shfl_xor((int)send, 1, 64);
  const u32 hi = even ? recv : o23;
  const u32 lo = even ? o01 : recv;
  const u32 dlo = __builtin_amdgcn_perm(hi, lo, 0x05040100u);
  const u32 dhi = __builtin_amdgcn_perm(hi, lo, 0x07060302u);
  const int n  = c.wid * 32 + nt * 16 + c.col;
  const int np = n & ~1;
  const int mA = mt * 16 + c.quad * 4 + (even ? 0 : 2);
  const int iA = mA * 512 + ((((np >> 3) ^ (mA & 7)) << 3) + (np & 7));
  const int mB = mA + 1;
  const int iB = mB * 512 + ((((np >> 3) ^ (mB & 7)) << 3) + (np & 7));
  *(u32*)&sA[iA] = dlo;
  *(u32*)&sA[iB] = dhi;
}

__device__ __forceinline__ void ln_reduce(const TileCtx& c, float* sRedF,
                                          f32x4 acc[4][2]) {
  #pragma unroll
  for (int mt = 0; mt < 4; ++mt) {
    float rs[4] = {0.f, 0.f, 0.f, 0.f}, rq[4] = {0.f, 0.f, 0.f, 0.f};
    #pragma unroll
    for (int reg = 0; reg < 4; ++reg)
      #pragma unroll
      for (int nt = 0; nt < 2; ++nt) {
        const float gt = acc[mt][nt][reg];
        rs[reg] += gt; rq[reg] += gt * gt;
      }
    #pragma unroll
    for (int msk = 8; msk >= 1; msk >>= 1)
      #pragma unroll
      for (int reg = 0; reg < 4; ++reg) {
        rs[reg] += __shfl_xor(rs[reg], msk, 64);
        rq[reg] += __shfl_xor(rq[reg], msk, 64);
      }
    if (c.col == 0) {
      #pragma unroll
      for (int reg = 0; reg < 4; ++reg) {
        const int m = mt * 16 + c.quad * 4 + reg;
        float2 sq; sq.x = rs[reg]; sq.y = rq[reg];
        *(float2*)&sRedF[m * 36 + c.wid * 2] = sq;
      }
    }
  }
  __syncthreads();
  if (c.tid < 64) {
    const int row = c.tid;
    float s = 0.f, q = 0.f;
    #pragma unroll
    for (int jj = 0; jj < 8; ++jj) {
      float4 v = *(float4*)&sRedF[row * 36 + jj * 4];
      s += v.x + v.z; q += v.y + v.w;
    }
    const float mu = s * (1.0f / H);
    const float rstd = rsqrtf(q * (1.0f / H) - mu * mu + 1e-3f);
    float2 mr; mr.x = mu; mr.y = rstd;
    *(float2*)&sRedF[2304 + row * 2] = mr;
  }
  __syncthreads();
}

// ---------------- ctx GRN as MFMA: 4 blocks x 64 batch rows ----------------
__global__ __launch_bounds__(1024)
void ctx_mfma(const float* __restrict__ in,       // [B, 512] flat
              const u16* __restrict__ Cp,         // W1cp | W2cp | Wgcp
              const float* __restrict__ b1c, const float* __restrict__ b2c,
              const float* __restrict__ bgc,
              const float* __restrict__ gamma_c, const float* __restrict__ beta_c,
              const float* __restrict__ Wsel, const float* __restrict__ bsel,
              float* __restrict__ sel_ws,         // [B, F]
              float* __restrict__ selw_out)       // [B, T, 1, F]
{
  __shared__ __align__(16) u16 smem[65536];
  u16* const sA  = smem;
  u16* const sB0 = smem + 32768;
  u16* const sB1 = smem + 49152;
  float* const sRedF = (float*)sB1;       // LN partials live in sB1 (free after last GEMM)
  float* const sZ   = (float*)sB0;        // [64][4] logits
  float* const sSel = (float*)sB0 + 256;  // [64][4] softmax

  TileCtx c;
  c.tid = threadIdx.x; c.wid = c.tid >> 6; c.lane = c.tid & 63;
  c.quad = c.lane >> 4; c.col = c.lane & 15;
  const int b0 = blockIdx.x * 64;
  const u16* W1cp = Cp;
  const u16* W2cp = Cp + 262144;
  const u16* Wgcp = Cp + 524288;

  // stage W1c chunk0
  glld16(W1cp + c.tid * 8, sB0 + c.tid * 8);
  glld16(W1cp + c.tid * 8 + 8192, sB0 + c.tid * 8 + 8192);

  // A0: flat -> sA bf16 (rotated k-group order to spread LDS write banks)
  {
    const int m = c.tid >> 4;
    const int kb = (c.tid & 15) * 32;
    const float* rowp = in + (size_t)(b0 + m) * H;
    #pragma unroll
    for (int gg = 0; gg < 4; ++gg) {
      const int ge = (gg + (c.tid & 15)) & 3;
      const int k = kb + ge * 8;
      float4 v0 = *(const float4*)&rowp[k];
      float4 v1 = *(const float4*)&rowp[k + 4];
      short8 pk;
      pk[0] = (short)f2bf(v0.x); pk[1] = (short)f2bf(v0.y);
      pk[2] = (short)f2bf(v0.z); pk[3] = (short)f2bf(v0.w);
      pk[4] = (short)f2bf(v1.x); pk[5] = (short)f2bf(v1.y);
      pk[6] = (short)f2bf(v1.z); pk[7] = (short)f2bf(v1.w);
      const int grp = (k >> 3) ^ (m & 7);
      *(short8*)&sA[m * 512 + grp * 8] = pk;
    }
  }
  __syncthreads();

  f32x4 acc[4][2];
  #pragma unroll
  for (int mt = 0; mt < 4; ++mt) { acc[mt][0] = (f32x4){0,0,0,0}; acc[mt][1] = (f32x4){0,0,0,0}; }

  // GEMM1: x1 = elu(flat@W1c + b1c) -> sA
  gemm_kloop<true>(c, W1cp, W2cp, sA, sB0, sB1, acc);
  {
    float bv[2] = { b1c[c.wid * 32 + c.col], b1c[c.wid * 32 + 16 + c.col] };
    #pragma unroll
    for (int mt = 0; mt < 4; ++mt)
      #pragma unroll
      for (int nt = 0; nt < 2; ++nt) {
        const float x0 = elu_f(acc[mt][nt][0] + bv[nt]);
        const float x1 = elu_f(acc[mt][nt][1] + bv[nt]);
        const float x2 = elu_f(acc[mt][nt][2] + bv[nt]);
        const float x3 = elu_f(acc[mt][nt][3] + bv[nt]);
        store_x2_pair(c, sA, mt, nt,
                      (u32)f2bf(x0) | ((u32)f2bf(x1) << 16),
                      (u32)f2bf(x2) | ((u32)f2bf(x3) << 16));
      }
  }
  __syncthreads();

  // GEMM2: x = x1@W2c + b2c -> sA only (re-read later; no xr regs)
  #pragma unroll
  for (int mt = 0; mt < 4; ++mt) { acc[mt][0] = (f32x4){0,0,0,0}; acc[mt][1] = (f32x4){0,0,0,0}; }
  gemm_kloop<true>(c, W2cp, Wgcp, sA, sB0, sB1, acc);
  {
    float bv[2] = { b2c[c.wid * 32 + c.col], b2c[c.wid * 32 + 16 + c.col] };
    #pragma unroll
    for (int mt = 0; mt < 4; ++mt)
      #pragma unroll
      for (int nt = 0; nt < 2; ++nt) {
        const float x0 = acc[mt][nt][0] + bv[nt];
        const float x1 = acc[mt][nt][1] + bv[nt];
        const float x2 = acc[mt][nt][2] + bv[nt];
        const float x3 = acc[mt][nt][3] + bv[nt];
        store_x2_pair(c, sA, mt, nt,
                      (u32)f2bf(x0) | ((u32)f2bf(x1) << 16),
                      (u32)f2bf(x2) | ((u32)f2bf(x3) << 16));
      }
  }
  __syncthreads();

  // GEMM3: gpre = x@Wgc; gate (x re-read from sA) + skip + LN -> ctx
  #pragma unroll
  for (int mt = 0; mt < 4; ++mt) { acc[mt][0] = (f32x4){0,0,0,0}; acc[mt][1] = (f32x4){0,0,0,0}; }
  gemm_kloop<false>(c, Wgcp, nullptr, sA, sB0, sB1, acc);
  {
    float bv[2] = { bgc[c.wid * 32 + c.col], bgc[c.wid * 32 + 16 + c.col] };
    #pragma unroll
    for (int mt = 0; mt < 4; ++mt)
      #pragma unroll
      for (int nt = 0; nt < 2; ++nt) {
        const int n = c.wid * 32 + nt * 16 + c.col;
        #pragma unroll
        for (int reg = 0; reg < 4; ++reg) {
          const int m = mt * 16 + c.quad * 4 + reg;
          const float xv = bf2f(sA[sA_idx(m, n)]);
          const float fl = in[(size_t)(b0 + m) * H + n];
          const float gv = sigmoid_f(acc[mt][nt][reg] + bv[nt]);
          acc[mt][nt][reg] = gv * xv + (1.0f - gv) * fl;
        }
      }
  }
  ln_reduce(c, sRedF, acc);   // in sB1; sA (x) untouched
  // ctx -> sA (plain [m][n] bf16 layout) for the sel dot
  {
    float gm[2], bt[2];
    #pragma unroll
    for (int nt = 0; nt < 2; ++nt) {
      const int n = c.wid * 32 + nt * 16 + c.col;
      gm[nt] = gamma_c[n]; bt[nt] = beta_c[n];
    }
    u16 cv[4][2][4];
    #pragma unroll
    for (int mt = 0; mt < 4; ++mt)
      #pragma unroll
      for (int reg = 0; reg < 4; ++reg) {
        const int m = mt * 16 + c.quad * 4 + reg;
        float2 mr = *(float2*)&sRedF[2304 + m * 2];
        #pragma unroll
        for (int nt = 0; nt < 2; ++nt)
          cv[mt][nt][reg] = f2bf(gm[nt] * ((acc[mt][nt][reg] - mr.x) * mr.y) + bt[nt]);
      }
    __syncthreads();
    #pragma unroll
    for (int mt = 0; mt < 4; ++mt)
      #pragma unroll
      for (int reg = 0; reg < 4; ++reg) {
        const int m = mt * 16 + c.quad * 4 + reg;
        #pragma unroll
        for (int nt = 0; nt < 2; ++nt)
          sA[m * 512 + c.wid * 32 + nt * 16 + c.col] = cv[mt][nt][reg];
      }
  }
  __syncthreads();

  // sel logits: 256 threads, (row, f)
  if (c.tid < 256) {
    const int r = c.tid >> 2, f = c.tid & 3;
    float z = bsel[f];
    const u16* rowp = &sA[r * 512];
    #pragma unroll 8
    for (int h = 0; h < H; ++h) z += bf2f(rowp[h]) * Wsel[h * NF + f];
    sZ[r * 4 + f] = z;
  }
  __syncthreads();
  if (c.tid < 64) {
    const int r = c.tid;
    float z0 = sZ[r*4], z1 = sZ[r*4+1], z2 = sZ[r*4+2], z3 = sZ[r*4+3];
    float mx = fmaxf(fmaxf(z0, z1), fmaxf(z2, z3));
    float e0 = __expf(z0-mx), e1 = __expf(z1-mx), e2 = __expf(z2-mx), e3 = __expf(z3-mx);
    float inv = __builtin_amdgcn_rcpf(e0 + e1 + e2 + e3);
    sSel[r*4]   = e0*inv; sSel[r*4+1] = e1*inv;
    sSel[r*4+2] = e2*inv; sSel[r*4+3] = e3*inv;
  }
  __syncthreads();
  if (c.tid < 256) {
    const int r = c.tid >> 2, f = c.tid & 3;
    sel_ws[(b0 + r) * NF + f] = sSel[r * 4 + f];
  }
  {
    const int m = c.tid >> 4;
    const int jb = (c.tid & 15) * 32;
    float s0 = sSel[m*4], s1 = sSel[m*4+1], s2 = sSel[m*4+2], s3 = sSel[m*4+3];
    float4 v; v.x = s0; v.y = s1; v.z = s2; v.w = s3;
    #pragma unroll
    for (int j = 0; j < 8; ++j)
      *(float4*)&selw_out[(size_t)(b0 + m) * H + jb + j * 4] = v;
  }
}

// ======================= 8-wave machinery (vsn_mfma) =======================
// Block: 512 thr = 8 waves. M-tile 64 rows. Wave wid owns cols wid*64..+63
// (nt=4 of 16). Per-thread frags: mt=4, nt=4 -> 16 MFMA per 8 ds_read_b128.
// Budget 256 regs (2 waves/SIMD): acc 64 + outacc 64 + frags; x2 re-read
// from sA in the gate phase instead of 32 packed regs -> no spills.

__device__ __forceinline__ void stage_chunk8(int tid, const u16* src, u16* dst) {
  glld16(src + tid * 8,         dst + tid * 8);
  glld16(src + tid * 8 + 4096,  dst + tid * 8 + 4096);
  glld16(src + tid * 8 + 8192,  dst + tid * 8 + 8192);
  glld16(src + tid * 8 + 12288, dst + tid * 8 + 12288);
}

template <bool PREFETCH_TAIL>
__device__ __forceinline__ void gemm_kloop8(const TileCtx& c, const u16* Wp,
                                            const u16* nextWp,
                                            u16* sA, u16* sB0, u16* sB1,
                                            f32x4 acc[4][4]) {
  #pragma unroll 1
  for (int kk = 0; kk < 16; ++kk) {
    if (kk < 15) {
      stage_chunk8(c.tid, Wp + (kk + 1) * 16384, (((kk + 1) & 1) ? sB1 : sB0));
    } else if (PREFETCH_TAIL) {
      stage_chunk8(c.tid, nextWp, sB0);
    }
    const u16* bp = ((kk & 1) ? sB1 : sB0) + c.wid * 2048 + c.lane * 8;
    short8 bb[4];
    #pragma unroll
    for (int nt = 0; nt < 4; ++nt) bb[nt] = *(const short8*)(bp + nt * 512);
    const int kq = kk * 4 + c.quad;
    const int s0 = (kq ^ (c.col & 7)) * 8;
    #pragma unroll
    for (int mt = 0; mt < 4; ++mt) {
      short8 a = *(const short8*)&sA[(mt * 16 + c.col) * 512 + s0];
      #pragma unroll
      for (int nt = 0; nt < 4; ++nt)
        acc[mt][nt] = MFMA16(a, bb[nt], acc[mt][nt]);
    }
    __syncthreads();
  }
}

// store one C-layout value-pair set into sA[m][k] bf16 via lane-pair exchange.
__device__ __forceinline__ void store_x2_pair_n(const TileCtx& c, u16* sA,
                                                int mt, int n, u32 o01, u32 o23) {
  const bool even = (c.lane & 1) == 0;
  const u32 send = even ? o23 : o01;
  const u32 recv = (u32)__shfl_xor((int)send, 1, 64);
  const u32 hi = even ? recv : o23;
  const u32 lo = even ? o01 : recv;
  const u32 dlo = __builtin_amdgcn_perm(hi, lo, 0x05040100u);
  const u32 dhi = __builtin_amdgcn_perm(hi, lo, 0x07060302u);
  const int np = n & ~1;
  const int mA = mt * 16 + c.quad * 4 + (even ? 0 : 2);
  const int iA = mA * 512 + ((((np >> 3) ^ (mA & 7)) << 3) + (np & 7));
  const int mB = mA + 1;
  const int iB = mB * 512 + ((((np >> 3) ^ (mB & 7)) << 3) + (np & 7));
  *(u32*)&sA[iA] = dlo;
  *(u32*)&sA[iB] = dhi;
}

// LN over 512 cols for 64 rows, 8-wave version. Partials stride 20 floats.
__device__ __forceinline__ void ln_reduce8(const TileCtx& c, float* sRedF,
                                           f32x4 acc[4][4]) {
  #pragma unroll
  for (int mt = 0; mt < 4; ++mt) {
    float rs[4] = {0.f, 0.f, 0.f, 0.f}, rq[4] = {0.f, 0.f, 0.f, 0.f};
    #pragma unroll
    for (int reg = 0; reg < 4; ++reg)
      #pragma unroll
      for (int nt = 0; nt < 4; ++nt) {
        const float gt = acc[mt][nt][reg];
        rs[reg] += gt; rq[reg] += gt * gt;
      }
    #pragma unroll
    for (int msk = 8; msk >= 1; msk >>= 1)
      #pragma unroll
      for (int reg = 0; reg < 4; ++reg) {
        rs[reg] += __shfl_xor(rs[reg], msk, 64);
        rq[reg] += __shfl_xor(rq[reg], msk, 64);
      }
    if (c.col == 0) {
      #pragma unroll
      for (int reg = 0; reg < 4; ++reg) {
        const int m = mt * 16 + c.quad * 4 + reg;
        float2 sq; sq.x = rs[reg]; sq.y = rq[reg];
        *(float2*)&sRedF[m * 20 + c.wid * 2] = sq;
      }
    }
  }
  __syncthreads();
  if (c.tid < 64) {
    const int row = c.tid;
    float s = 0.f, q = 0.f;
    #pragma unroll
    for (int jj = 0; jj < 4; ++jj) {
      float4 v = *(float4*)&sRedF[row * 20 + jj * 4];
      s += v.x + v.z; q += v.y + v.w;
    }
    const float mu = s * (1.0f / H);
    const float rstd = rsqrtf(q * (1.0f / H) - mu * mu + 1e-3f);
    float2 mr; mr.x = mu; mr.y = rstd;
    *(float2*)&sRedF[1280 + row * 2] = mr;
  }
  __syncthreads();
}

// ---------------- vsn_mfma: per-variable GRNs + weighted selection ----------------
__global__ __launch_bounds__(512, 2)
void vsn_mfma(const float* __restrict__ in,     // [MTOT, F]
              const float* __restrict__ w1, const float* __restrict__ b1,
              const float* __restrict__ b2, const float* __restrict__ bg,
              const float* __restrict__ gamma, const float* __restrict__ beta,
              const u16* __restrict__ W2p, const u16* __restrict__ Wgp,
              const float* __restrict__ sel_ws,  // [B, F]
              float* __restrict__ out)           // [MTOT, H]
{
  __shared__ __align__(16) u16 smem[65536];
  u16* const sA  = smem;              // [64][512] bf16 XOR-swizzled, 64 KB
  u16* const sB0 = smem + 32768;      // 32 KB chunk
  u16* const sB1 = smem + 49152;      // 32 KB chunk
  float* const sRedF = (float*)sB1;   // LN partials in sB1 (free after GEMM2)
  float* const sF = (float*)smem;     // fp32 [64][512] out-bounce (whole smem)

  TileCtx c;
  c.tid = threadIdx.x; c.wid = c.tid >> 6; c.lane = c.tid & 63;
  c.quad = c.lane >> 4; c.col = c.lane & 15;
  const int row0 = blockIdx.x * 64;
  const int bidx = row0 >> 7;

  f32x4 outacc[4][4];
  #pragma unroll
  for (int mt = 0; mt < 4; ++mt)
    #pragma unroll
    for (int nt = 0; nt < 4; ++nt) outacc[mt][nt] = (f32x4){0,0,0,0};

  // stage f=0 GEMM1 chunk0 (overlapped by first A1 phase)
  stage_chunk8(c.tid, W2p, sB0);

  #pragma unroll 1
  for (int f = 0; f < NF; ++f) {
    const u16* W2f = W2p + (size_t)f * 262144;
    const u16* Wgf = Wgp + (size_t)f * 262144;
    const u16* W2n = W2p + (size_t)((f + 1) & 3) * 262144;  // next f's GEMM1 (wraps, harmless)

    // A1: sA[m][k] = bf16(elu(v[m]*w1[k] + b1[k])), rotated k-group order
    {
      const int m  = c.tid >> 3;
      const int kb = (c.tid & 7) * 64;
      const float v = in[(size_t)(row0 + m) * NF + f];
      const float* w1f = w1 + f * H;
      const float* b1f = b1 + f * H;
      #pragma unroll
      for (int gg = 0; gg < 8; ++gg) {
        const int ge = (gg + (c.tid & 7)) & 7;
        const int k = kb + ge * 8;
        float4 wv0 = *(const float4*)&w1f[k];
        float4 wv1 = *(const float4*)&w1f[k + 4];
        float4 bv0 = *(const float4*)&b1f[k];
        float4 bv1 = *(const float4*)&b1f[k + 4];
        short8 pk;
        pk[0] = (short)f2bf(elu_f(fmaf(v, wv0.x, bv0.x)));
        pk[1] = (short)f2bf(elu_f(fmaf(v, wv0.y, bv0.y)));
        pk[2] = (short)f2bf(elu_f(fmaf(v, wv0.z, bv0.z)));
        pk[3] = (short)f2bf(elu_f(fmaf(v, wv0.w, bv0.w)));
        pk[4] = (short)f2bf(elu_f(fmaf(v, wv1.x, bv1.x)));
        pk[5] = (short)f2bf(elu_f(fmaf(v, wv1.y, bv1.y)));
        pk[6] = (short)f2bf(elu_f(fmaf(v, wv1.z, bv1.z)));
        pk[7] = (short)f2bf(elu_f(fmaf(v, wv1.w, bv1.w)));
        const int grp = (k >> 3) ^ (m & 7);
        *(short8*)&sA[m * 512 + grp * 8] = pk;
      }
    }
    __syncthreads();

    f32x4 acc[4][4];
    #pragma unroll
    for (int mt = 0; mt < 4; ++mt)
      #pragma unroll
      for (int nt = 0; nt < 4; ++nt) acc[mt][nt] = (f32x4){0,0,0,0};

    // GEMM1 (tail-prefetches Wgf chunk0 into sB0)
    gemm_kloop8<true>(c, W2f, Wgf, sA, sB0, sB1, acc);

    // epilogue1: x2 = acc + b2 -> sA only (re-read in gate phase; no x2p regs)
    {
      float bv[4];
      #pragma unroll
      for (int nt = 0; nt < 4; ++nt) bv[nt] = b2[f * H + c.wid * 64 + nt * 16 + c.col];
      #pragma unroll
      for (int mt = 0; mt < 4; ++mt)
        #pragma unroll
        for (int nt = 0; nt < 4; ++nt) {
          const float x0 = acc[mt][nt][0] + bv[nt];
          const float x1 = acc[mt][nt][1] + bv[nt];
          const float x2 = acc[mt][nt][2] + bv[nt];
          const float x3 = acc[mt][nt][3] + bv[nt];
          const u32 o01 = (u32)f2bf(x0) | ((u32)f2bf(x1) << 16);
          const u32 o23 = (u32)f2bf(x2) | ((u32)f2bf(x3) << 16);
          store_x2_pair_n(c, sA, mt, c.wid * 64 + nt * 16 + c.col, o01, o23);
        }
    }
    __syncthreads();

    // GEMM2 (tail-prefetches next f's W2 chunk0 -> overlaps gate+LN epilogue)
    #pragma unroll
    for (int mt = 0; mt < 4; ++mt)
      #pragma unroll
      for (int nt = 0; nt < 4; ++nt) acc[mt][nt] = (f32x4){0,0,0,0};
    gemm_kloop8<true>(c, Wgf, W2n, sA, sB0, sB1, acc);

    // gate (x2 re-read from sA) + LN + weighted accumulate
    {
      const float selw = sel_ws[bidx * NF + f];
      float bv[4];
      #pragma unroll
      for (int nt = 0; nt < 4; ++nt) bv[nt] = bg[f * H + c.wid * 64 + nt * 16 + c.col];
      #pragma unroll
      for (int mt = 0; mt < 4; ++mt) {
        float vr[4];
        #pragma unroll
        for (int reg = 0; reg < 4; ++reg)
          vr[reg] = in[(size_t)(row0 + mt * 16 + c.quad * 4 + reg) * NF + f];
        #pragma unroll
        for (int nt = 0; nt < 4; ++nt) {
          const int n = c.wid * 64 + nt * 16 + c.col;
          #pragma unroll
          for (int reg = 0; reg < 4; ++reg) {
            const int m = mt * 16 + c.quad * 4 + reg;
            const float x2v = bf2f(sA[sA_idx(m, n)]);
            const float gv = sigmoid_f(acc[mt][nt][reg] + bv[nt]);
            acc[mt][nt][reg] = gv * x2v + (1.0f - gv) * vr[reg];
          }
        }
      }
      ln_reduce8(c, sRedF, acc);   // in sB1; sA untouched (x2 already consumed)
      float gm[4], bt[4];
      #pragma unroll
      for (int nt = 0; nt < 4; ++nt) {
        const int n = f * H + c.wid * 64 + nt * 16 + c.col;
        gm[nt] = gamma[n]; bt[nt] = beta[n];
      }
      #pragma unroll
      for (int mt = 0; mt < 4; ++mt)
        #pragma unroll
        for (int reg = 0; reg < 4; ++reg) {
          const int m = mt * 16 + c.quad * 4 + reg;
          float2 mr = *(float2*)&sRedF[1280 + m * 2];
          #pragma unroll
          for (int nt = 0; nt < 4; ++nt) {
            const float tv = gm[nt] * ((acc[mt][nt][reg] - mr.x) * mr.y) + bt[nt];
            outacc[mt][nt][reg] = fmaf(selw, tv, outacc[mt][nt][reg]);
          }
        }
      __syncthreads();   // sRedF/sA reads done before next f's writes
    }
  }

  // out-bounce: outacc -> sF fp32 [64][512], then contiguous f32x4 NT stores
  #pragma unroll
  for (int mt = 0; mt < 4; ++mt)
    #pragma unroll
    for (int reg = 0; reg < 4; ++reg) {
      const int m = mt * 16 + c.quad * 4 + reg;
      #pragma unroll
      for (int nt = 0; nt < 4; ++nt)
        sF[m * 512 + c.wid * 64 + nt * 16 + c.col] = outacc[mt][nt][reg];
    }
  __syncthreads();
  {
    float* const obase = out + (size_t)row0 * H;
    #pragma unroll
    for (int p = 0; p < 16; ++p) {
      const int flat = p * 2048 + c.tid * 4;
      f32x4 v = *(f32x4*)&sF[flat];
      __builtin_nontemporal_store(v, (f32x4*)&obase[flat]);
    }
  }
}

extern "C" void kernel_launch(void* const* d_in, const int* in_sizes, int n_in,
                              void* d_out, int out_size, void* d_ws, size_t ws_size,
                              hipStream_t stream) {
  const float* in_     = (const float*)d_in[0];
  const float* W1c     = (const float*)d_in[1];
  const float* b1c     = (const float*)d_in[2];
  const float* W2c     = (const float*)d_in[3];
  const float* b2c     = (const float*)d_in[4];
  const float* Wgc     = (const float*)d_in[5];
  const float* bgc     = (const float*)d_in[6];
  const float* gamma_c = (const float*)d_in[7];
  const float* beta_c  = (const float*)d_in[8];
  const float* Wsel    = (const float*)d_in[9];
  const float* bsel    = (const float*)d_in[10];
  const float* w1      = (const float*)d_in[11];
  const float* b1v     = (const float*)d_in[12];
  const float* W2      = (const float*)d_in[13];
  const float* b2v     = (const float*)d_in[14];
  const float* Wg      = (const float*)d_in[15];
  const float* bgv     = (const float*)d_in[16];
  const float* gma     = (const float*)d_in[17];
  const float* bta     = (const float*)d_in[18];

  float* out_sel = (float*)d_out;                      // [MTOT, H]
  float* out_w   = (float*)d_out + (size_t)MTOT * H;   // [B, T, 1, F]

  float* sel_ws = (float*)d_ws;                        // 4 KB
  u16*   W2p    = (u16*)((char*)d_ws + 4096);          // 2 MB
  u16*   Wgp    = W2p + (size_t)NF * H * H;            // 2 MB
  u16*   Cp     = Wgp + (size_t)NF * H * H;            // 1.5 MB (W1c|W2c|Wgc)

  hipLaunchKernelGGL(pack_weights, dim3(1408), dim3(256), 0, stream,
                     W2, Wg, W1c, W2c, Wgc, W2p, Wgp, Cp);
  hipLaunchKernelGGL(ctx_mfma, dim3(4), dim3(1024), 0, stream,
                     in_, Cp, b1c, b2c, bgc, gamma_c, beta_c,
                     Wsel, bsel, sel_ws, out_w);
  hipLaunchKernelGGL(vsn_mfma, dim3(MTOT / 64), dim3(512), 0, stream,
                     in_, w1, b1v, b2v, bgv, gma, bta, W2p, Wgp, sel_ws, out_sel);
}

// Round 4
// 548.262 us; speedup vs baseline: 1.1023x; 1.1023x over previous
//
#include <hip/hip_runtime.h>
#include <math.h>

// VariableSelectionNetwork — round 6.
// Base = round 4 (346us best). ONE structural change: counted-vmcnt k-loops
// (T3+T4+T5 template). The old __syncthreads per kk drained vmcnt(0) -> waited
// for the JUST-ISSUED next-chunk glld16s every kk (128x exposed L2/HBM latency,
// the m97-structure stall). New schedule per kk:
//   issue stage(kk+1) -> s_waitcnt vmcnt(N) [waits chunk kk, issued 1 iter ago]
//   -> s_barrier -> ds_read + setprio(1) MFMA setprio(0)
//   -> lgkmcnt(0) -> s_barrier [buffer safe to overwrite next iter]
// Entry invariant (0 outstanding) provided by existing __syncthreads before
// each kloop. Side fix: ctx sel-dot parallelized 4-way (1024 thr, 128 h each).

#define H 512
#define NF 4
#define MTOT 32768

typedef unsigned short u16;
typedef unsigned int u32;
typedef __attribute__((ext_vector_type(8))) short short8;   // 8 bf16 = 4 VGPRs
typedef __attribute__((ext_vector_type(4))) float f32x4;    // MFMA C/D

__device__ __forceinline__ u16 f2bf(float x) {
  union { float f; u32 u; } v; v.f = x;
  return (u16)((v.u + 0x7fffu + ((v.u >> 16) & 1u)) >> 16);  // RNE
}
__device__ __forceinline__ float bf2f(u32 h16) {
  union { u32 u; float f; } v; v.u = h16 << 16;
  return v.f;
}
__device__ __forceinline__ float elu_f(float x) {
  return x > 0.0f ? x : (__expf(x) - 1.0f);
}
__device__ __forceinline__ float sigmoid_f(float x) {
  return __builtin_amdgcn_rcpf(1.0f + __expf(-x));
}

// async global->LDS, 16B per lane; LDS dest = wave-uniform base + lane*16.
__device__ __forceinline__ void glld16(const void* g, void* l) {
  __builtin_amdgcn_global_load_lds(
      (const __attribute__((address_space(1))) u32*)(unsigned long long)(uintptr_t)g,
      (__attribute__((address_space(3))) u32*)(u32)(uintptr_t)l, 16, 0, 0);
}

#define MFMA16(a, b, c) __builtin_amdgcn_mfma_f32_16x16x32_bf16((a), (b), (c), 0, 0, 0)

// ---------------- pack_weights: fp32 -> bf16 B-fragment-major ----------------
// Packed per matrix: (((kk*32 + ntg)*64 + lane)*8 + j); chunk kk = 32k x 512n
// = 32KB contiguous. mats 0-3 W2[f], 4-7 Wg[f], 8 W1c, 9 W2c, 10 Wgc.
__global__ __launch_bounds__(256)
void pack_weights(const float* __restrict__ W2, const float* __restrict__ Wg,
                  const float* __restrict__ W1c, const float* __restrict__ W2c,
                  const float* __restrict__ Wgc,
                  u16* __restrict__ W2p, u16* __restrict__ Wgp, u16* __restrict__ Cp) {
  int g = blockIdx.x * 256 + threadIdx.x;       // 0 .. 11*32768-1
  int r = g & 32767; int mat = g >> 15;
  if (mat >= 11) return;
  int lane = r & 63, nt = (r >> 6) & 31, kk = (r >> 11) & 15;
  const float* src; u16* dst;
  if (mat < 4)      { src = W2 + (size_t)mat * 262144;       dst = W2p + (size_t)mat * 262144; }
  else if (mat < 8) { src = Wg + (size_t)(mat - 4) * 262144; dst = Wgp + (size_t)(mat - 4) * 262144; }
  else              { src = (mat == 8 ? W1c : (mat == 9 ? W2c : Wgc));
                      dst = Cp + (size_t)(mat - 8) * 262144; }
  dst += (((size_t)kk * 32 + nt) * 64 + lane) * 8;
  int n  = nt * 16 + (lane & 15);
  int k0 = kk * 32 + (lane >> 4) * 8;
  short8 pk;
  #pragma unroll
  for (int j = 0; j < 8; ++j) pk[j] = (short)f2bf(src[(size_t)(k0 + j) * H + n]);
  *(short8*)dst = pk;
}

struct TileCtx {
  int tid, wid, lane, quad, col;
};

// ======================= 16-wave machinery (ctx_mfma) =======================
// Block: 1024 thr = 16 waves. M-tile 64 rows. Wave wid owns cols wid*32..+31
// (nt=2 of 16). Per-thread frags: mt=4, nt=2. sA: 64KB bf16 [m][k] XOR-swizzled
// (16B groups, grp = (k>>3) ^ (m&7)). sB: 2 x 32KB chunk buffers (BK=32).
// Counted-vmcnt schedule; entry requires 0 outstanding vmem + chunk0 in sB0.

template <bool PREFETCH_TAIL>
__device__ __forceinline__ void gemm_kloop(const TileCtx& c, const u16* Wp,
                                           const u16* nextWp,
                                           u16* sA, u16* sB0, u16* sB1,
                                           f32x4 acc[4][2]) {
  #pragma unroll 1
  for (int kk = 0; kk < 16; ++kk) {
    if (kk < 15) {
      const u16* src = Wp + (kk + 1) * 16384 + c.tid * 8;
      u16* dst = (((kk + 1) & 1) ? sB1 : sB0) + c.tid * 8;
      glld16(src, dst);
      glld16(src + 8192, dst + 8192);
      asm volatile("s_waitcnt vmcnt(2)" ::: "memory");
    } else if (PREFETCH_TAIL) {
      const u16* src = nextWp + c.tid * 8;
      glld16(src, sB0 + c.tid * 8);
      glld16(src + 8192, sB0 + c.tid * 8 + 8192);
      asm volatile("s_waitcnt vmcnt(2)" ::: "memory");
    } else {
      asm volatile("s_waitcnt vmcnt(0)" ::: "memory");
    }
    __builtin_amdgcn_s_barrier();            // chunk kk visible to all waves
    __builtin_amdgcn_sched_barrier(0);
    const u16* bp = ((kk & 1) ? sB1 : sB0) + c.wid * 1024 + c.lane * 8;
    short8 bb0 = *(const short8*)(bp);
    short8 bb1 = *(const short8*)(bp + 512);
    const int kq = kk * 4 + c.quad;
    const int s0 = (kq ^ (c.col & 7)) * 8;
    short8 a0 = *(const short8*)&sA[(     c.col) * 512 + s0];
    short8 a1 = *(const short8*)&sA[(16 + c.col) * 512 + s0];
    short8 a2 = *(const short8*)&sA[(32 + c.col) * 512 + s0];
    short8 a3 = *(const short8*)&sA[(48 + c.col) * 512 + s0];
    __builtin_amdgcn_s_setprio(1);
    acc[0][0] = MFMA16(a0, bb0, acc[0][0]); acc[0][1] = MFMA16(a0, bb1, acc[0][1]);
    acc[1][0] = MFMA16(a1, bb0, acc[1][0]); acc[1][1] = MFMA16(a1, bb1, acc[1][1]);
    acc[2][0] = MFMA16(a2, bb0, acc[2][0]); acc[2][1] = MFMA16(a2, bb1, acc[2][1]);
    acc[3][0] = MFMA16(a3, bb0, acc[3][0]); acc[3][1] = MFMA16(a3, bb1, acc[3][1]);
    __builtin_amdgcn_s_setprio(0);
    asm volatile("s_waitcnt lgkmcnt(0)" ::: "memory");  // ds_reads of buf[kk&1] retired
    __builtin_amdgcn_sched_barrier(0);
    __builtin_amdgcn_s_barrier();            // safe to overwrite buf[kk&1] next iter
  }
}

__device__ __forceinline__ void store_x2_pair(const TileCtx& c, u16* sA,
                                              int mt, int nt, u32 o01, u32 o23) {
  const bool even = (c.lane & 1) == 0;
  const u32 send = even ? o23 : o01;
  const u32 recv = (u32)__shfl_xor((int)send, 1, 64);
  const u32 hi = even ? recv : o23;
  const u32 lo = even ? o01 : recv;
  const u32 dlo = __builtin_amdgcn_perm(hi, lo, 0x05040100u);
  const u32 dhi = __builtin_amdgcn_perm(hi, lo, 0x07060302u);
  const int n  = c.wid * 32 + nt * 16 + c.col;
  const int np = n & ~1;
  const int mA = mt * 16 + c.quad * 4 + (even ? 0 : 2);
  const int iA = mA * 512 + ((((np >> 3) ^ (mA & 7)) << 3) + (np & 7));
  const int mB = mA + 1;
  const int iB = mB * 512 + ((((np >> 3) ^ (mB & 7)) << 3) + (np & 7));
  *(u32*)&sA[iA] = dlo;
  *(u32*)&sA[iB] = dhi;
}

__device__ __forceinline__ void ln_reduce(const TileCtx& c, float* sRedF,
                                          f32x4 acc[4][2]) {
  #pragma unroll
  for (int mt = 0; mt < 4; ++mt) {
    float rs[4] = {0.f, 0.f, 0.f, 0.f}, rq[4] = {0.f, 0.f, 0.f, 0.f};
    #pragma unroll
    for (int reg = 0; reg < 4; ++reg)
      #pragma unroll
      for (int nt = 0; nt < 2; ++nt) {
        const float gt = acc[mt][nt][reg];
        rs[reg] += gt; rq[reg] += gt * gt;
      }
    #pragma unroll
    for (int msk = 8; msk >= 1; msk >>= 1)
      #pragma unroll
      for (int reg = 0; reg < 4; ++reg) {
        rs[reg] += __shfl_xor(rs[reg], msk, 64);
        rq[reg] += __shfl_xor(rq[reg], msk, 64);
      }
    if (c.col == 0) {
      #pragma unroll
      for (int reg = 0; reg < 4; ++reg) {
        const int m = mt * 16 + c.quad * 4 + reg;
        float2 sq; sq.x = rs[reg]; sq.y = rq[reg];
        *(float2*)&sRedF[m * 36 + c.wid * 2] = sq;
      }
    }
  }
  __syncthreads();
  if (c.tid < 64) {
    const int row = c.tid;
    float s = 0.f, q = 0.f;
    #pragma unroll
    for (int jj = 0; jj < 8; ++jj) {
      float4 v = *(float4*)&sRedF[row * 36 + jj * 4];
      s += v.x + v.z; q += v.y + v.w;
    }
    const float mu = s * (1.0f / H);
    const float rstd = rsqrtf(q * (1.0f / H) - mu * mu + 1e-3f);
    float2 mr; mr.x = mu; mr.y = rstd;
    *(float2*)&sRedF[2304 + row * 2] = mr;
  }
  __syncthreads();
}

// ---------------- ctx GRN as MFMA: 4 blocks x 64 batch rows ----------------
__global__ __launch_bounds__(1024)
void ctx_mfma(const float* __restrict__ in,       // [B, 512] flat
              const u16* __restrict__ Cp,         // W1cp | W2cp | Wgcp
              const float* __restrict__ b1c, const float* __restrict__ b2c,
              const float* __restrict__ bgc,
              const float* __restrict__ gamma_c, const float* __restrict__ beta_c,
              const float* __restrict__ Wsel, const float* __restrict__ bsel,
              float* __restrict__ sel_ws,         // [B, F]
              float* __restrict__ selw_out)       // [B, T, 1, F]
{
  __shared__ __align__(16) u16 smem[65536];
  u16* const sA  = smem;
  u16* const sB0 = smem + 32768;
  u16* const sB1 = smem + 49152;
  float* const sRedF = (float*)smem;       // LN partials overlay sA (dead there)
  float* const sZ   = (float*)sB0;         // [256][4] logit partials
  float* const sSel = (float*)sB0 + 1024;  // [64][4] softmax

  TileCtx c;
  c.tid = threadIdx.x; c.wid = c.tid >> 6; c.lane = c.tid & 63;
  c.quad = c.lane >> 4; c.col = c.lane & 15;
  const int b0 = blockIdx.x * 64;
  const u16* W1cp = Cp;
  const u16* W2cp = Cp + 262144;
  const u16* Wgcp = Cp + 524288;

  // stage W1c chunk0
  glld16(W1cp + c.tid * 8, sB0 + c.tid * 8);
  glld16(W1cp + c.tid * 8 + 8192, sB0 + c.tid * 8 + 8192);

  // A0: flat -> sA bf16 (rotated k-group order to spread LDS write banks)
  {
    const int m = c.tid >> 4;
    const int kb = (c.tid & 15) * 32;
    const float* rowp = in + (size_t)(b0 + m) * H;
    #pragma unroll
    for (int gg = 0; gg < 4; ++gg) {
      const int ge = (gg + (c.tid & 15)) & 3;
      const int k = kb + ge * 8;
      float4 v0 = *(const float4*)&rowp[k];
      float4 v1 = *(const float4*)&rowp[k + 4];
      short8 pk;
      pk[0] = (short)f2bf(v0.x); pk[1] = (short)f2bf(v0.y);
      pk[2] = (short)f2bf(v0.z); pk[3] = (short)f2bf(v0.w);
      pk[4] = (short)f2bf(v1.x); pk[5] = (short)f2bf(v1.y);
      pk[6] = (short)f2bf(v1.z); pk[7] = (short)f2bf(v1.w);
      const int grp = (k >> 3) ^ (m & 7);
      *(short8*)&sA[m * 512 + grp * 8] = pk;
    }
  }
  __syncthreads();   // drains vmcnt -> kloop entry invariant holds

  f32x4 acc[4][2];
  #pragma unroll
  for (int mt = 0; mt < 4; ++mt) { acc[mt][0] = (f32x4){0,0,0,0}; acc[mt][1] = (f32x4){0,0,0,0}; }

  // GEMM1: x1 = elu(flat@W1c + b1c) -> sA
  gemm_kloop<true>(c, W1cp, W2cp, sA, sB0, sB1, acc);
  {
    float bv[2] = { b1c[c.wid * 32 + c.col], b1c[c.wid * 32 + 16 + c.col] };
    #pragma unroll
    for (int mt = 0; mt < 4; ++mt)
      #pragma unroll
      for (int nt = 0; nt < 2; ++nt) {
        const float x0 = elu_f(acc[mt][nt][0] + bv[nt]);
        const float x1 = elu_f(acc[mt][nt][1] + bv[nt]);
        const float x2 = elu_f(acc[mt][nt][2] + bv[nt]);
        const float x3 = elu_f(acc[mt][nt][3] + bv[nt]);
        store_x2_pair(c, sA, mt, nt,
                      (u32)f2bf(x0) | ((u32)f2bf(x1) << 16),
                      (u32)f2bf(x2) | ((u32)f2bf(x3) << 16));
      }
  }
  __syncthreads();

  // GEMM2: x = x1@W2c + b2c (keep fp32 in regs, also -> sA)
  float xr[4][2][4];
  #pragma unroll
  for (int mt = 0; mt < 4; ++mt) { acc[mt][0] = (f32x4){0,0,0,0}; acc[mt][1] = (f32x4){0,0,0,0}; }
  gemm_kloop<true>(c, W2cp, Wgcp, sA, sB0, sB1, acc);
  {
    float bv[2] = { b2c[c.wid * 32 + c.col], b2c[c.wid * 32 + 16 + c.col] };
    #pragma unroll
    for (int mt = 0; mt < 4; ++mt)
      #pragma unroll
      for (int nt = 0; nt < 2; ++nt) {
        #pragma unroll
        for (int reg = 0; reg < 4; ++reg) xr[mt][nt][reg] = acc[mt][nt][reg] + bv[nt];
        store_x2_pair(c, sA, mt, nt,
                      (u32)f2bf(xr[mt][nt][0]) | ((u32)f2bf(xr[mt][nt][1]) << 16),
                      (u32)f2bf(xr[mt][nt][2]) | ((u32)f2bf(xr[mt][nt][3]) << 16));
      }
  }
  __syncthreads();

  // GEMM3: gpre = x@Wgc; gate + skip + LN -> ctx
  #pragma unroll
  for (int mt = 0; mt < 4; ++mt) { acc[mt][0] = (f32x4){0,0,0,0}; acc[mt][1] = (f32x4){0,0,0,0}; }
  gemm_kloop<false>(c, Wgcp, nullptr, sA, sB0, sB1, acc);
  {
    float bv[2] = { bgc[c.wid * 32 + c.col], bgc[c.wid * 32 + 16 + c.col] };
    #pragma unroll
    for (int mt = 0; mt < 4; ++mt)
      #pragma unroll
      for (int nt = 0; nt < 2; ++nt) {
        const int n = c.wid * 32 + nt * 16 + c.col;
        #pragma unroll
        for (int reg = 0; reg < 4; ++reg) {
          const int m = mt * 16 + c.quad * 4 + reg;
          const float fl = in[(size_t)(b0 + m) * H + n];
          const float gv = sigmoid_f(acc[mt][nt][reg] + bv[nt]);
          acc[mt][nt][reg] = gv * xr[mt][nt][reg] + (1.0f - gv) * fl;
        }
      }
  }
  ln_reduce(c, sRedF, acc);   // overlays sA; sA re-written below after LN
  // ctx -> sA (plain [m][n] bf16 layout) for the sel dot
  {
    float gm[2], bt[2];
    #pragma unroll
    for (int nt = 0; nt < 2; ++nt) {
      const int n = c.wid * 32 + nt * 16 + c.col;
      gm[nt] = gamma_c[n]; bt[nt] = beta_c[n];
    }
    u16 cv[4][2][4];
    #pragma unroll
    for (int mt = 0; mt < 4; ++mt)
      #pragma unroll
      for (int reg = 0; reg < 4; ++reg) {
        const int m = mt * 16 + c.quad * 4 + reg;
        float2 mr = *(float2*)&sRedF[2304 + m * 2];
        #pragma unroll
        for (int nt = 0; nt < 2; ++nt)
          cv[mt][nt][reg] = f2bf(gm[nt] * ((acc[mt][nt][reg] - mr.x) * mr.y) + bt[nt]);
      }
    __syncthreads();   // sRedF reads done; sA region reusable
    #pragma unroll
    for (int mt = 0; mt < 4; ++mt)
      #pragma unroll
      for (int reg = 0; reg < 4; ++reg) {
        const int m = mt * 16 + c.quad * 4 + reg;
        #pragma unroll
        for (int nt = 0; nt < 2; ++nt)
          sA[m * 512 + c.wid * 32 + nt * 16 + c.col] = cv[mt][nt][reg];
      }
  }
  __syncthreads();

  // sel logits: all 1024 threads, (row, f, quarter): each dots 128 h
  {
    const int r = c.tid >> 4, fq = (c.tid >> 2) & 3, p = c.tid & 3;
    float z = 0.f;
    const u16* rowp = &sA[r * 512 + p * 128];
    const float* wp = Wsel + (size_t)p * 128 * NF + fq;
    #pragma unroll 8
    for (int h = 0; h < 128; ++h) z += bf2f(rowp[h]) * wp[h * NF];
    sZ[((r * 4 + fq) << 2) + p] = z;
  }
  __syncthreads();
  if (c.tid < 64) {
    const int r = c.tid;
    float zz[4];
    #pragma unroll
    for (int ff = 0; ff < 4; ++ff) {
      float4 v = *(float4*)&sZ[(r * 4 + ff) << 2];
      zz[ff] = v.x + v.y + v.z + v.w + bsel[ff];
    }
    float mx = fmaxf(fmaxf(zz[0], zz[1]), fmaxf(zz[2], zz[3]));
    float e0 = __expf(zz[0]-mx), e1 = __expf(zz[1]-mx), e2 = __expf(zz[2]-mx), e3 = __expf(zz[3]-mx);
    float inv = __builtin_amdgcn_rcpf(e0 + e1 + e2 + e3);
    sSel[r*4]   = e0*inv; sSel[r*4+1] = e1*inv;
    sSel[r*4+2] = e2*inv; sSel[r*4+3] = e3*inv;
  }
  __syncthreads();
  if (c.tid < 256) {
    const int r = c.tid >> 2, f = c.tid & 3;
    sel_ws[(b0 + r) * NF + f] = sSel[r * 4 + f];
  }
  {
    const int m = c.tid >> 4;
    const int jb = (c.tid & 15) * 32;
    float s0 = sSel[m*4], s1 = sSel[m*4+1], s2 = sSel[m*4+2], s3 = sSel[m*4+3];
    float4 v; v.x = s0; v.y = s1; v.z = s2; v.w = s3;
    #pragma unroll
    for (int j = 0; j < 8; ++j)
      *(float4*)&selw_out[(size_t)(b0 + m) * H + jb + j * 4] = v;
  }
}

// ======================= 8-wave machinery (vsn_mfma) =======================
// Block: 512 thr = 8 waves. M-tile 64 rows. Wave wid owns cols wid*64..+63
// (nt=4 of 16). Per-thread frags: mt=4, nt=4 -> 16 MFMA per 8 ds_read_b128.

__device__ __forceinline__ void stage_chunk8(int tid, const u16* src, u16* dst) {
  glld16(src + tid * 8,         dst + tid * 8);
  glld16(src + tid * 8 + 4096,  dst + tid * 8 + 4096);
  glld16(src + tid * 8 + 8192,  dst + tid * 8 + 8192);
  glld16(src + tid * 8 + 12288, dst + tid * 8 + 12288);
}

template <bool PREFETCH_TAIL>
__device__ __forceinline__ void gemm_kloop8(const TileCtx& c, const u16* Wp,
                                            const u16* nextWp,
                                            u16* sA, u16* sB0, u16* sB1,
                                            f32x4 acc[4][4]) {
  #pragma unroll 1
  for (int kk = 0; kk < 16; ++kk) {
    if (kk < 15) {
      stage_chunk8(c.tid, Wp + (kk + 1) * 16384, (((kk + 1) & 1) ? sB1 : sB0));
      asm volatile("s_waitcnt vmcnt(4)" ::: "memory");
    } else if (PREFETCH_TAIL) {
      stage_chunk8(c.tid, nextWp, sB0);
      asm volatile("s_waitcnt vmcnt(4)" ::: "memory");
    } else {
      asm volatile("s_waitcnt vmcnt(0)" ::: "memory");
    }
    __builtin_amdgcn_s_barrier();            // chunk kk visible to all waves
    __builtin_amdgcn_sched_barrier(0);
    const u16* bp = ((kk & 1) ? sB1 : sB0) + c.wid * 2048 + c.lane * 8;
    short8 bb[4];
    #pragma unroll
    for (int nt = 0; nt < 4; ++nt) bb[nt] = *(const short8*)(bp + nt * 512);
    const int kq = kk * 4 + c.quad;
    const int s0 = (kq ^ (c.col & 7)) * 8;
    short8 a0 = *(const short8*)&sA[(     c.col) * 512 + s0];
    short8 a1 = *(const short8*)&sA[(16 + c.col) * 512 + s0];
    short8 a2 = *(const short8*)&sA[(32 + c.col) * 512 + s0];
    short8 a3 = *(const short8*)&sA[(48 + c.col) * 512 + s0];
    __builtin_amdgcn_s_setprio(1);
    #pragma unroll
    for (int nt = 0; nt < 4; ++nt) acc[0][nt] = MFMA16(a0, bb[nt], acc[0][nt]);
    #pragma unroll
    for (int nt = 0; nt < 4; ++nt) acc[1][nt] = MFMA16(a1, bb[nt], acc[1][nt]);
    #pragma unroll
    for (int nt = 0; nt < 4; ++nt) acc[2][nt] = MFMA16(a2, bb[nt], acc[2][nt]);
    #pragma unroll
    for (int nt = 0; nt < 4; ++nt) acc[3][nt] = MFMA16(a3, bb[nt], acc[3][nt]);
    __builtin_amdgcn_s_setprio(0);
    asm volatile("s_waitcnt lgkmcnt(0)" ::: "memory");  // ds_reads retired
    __builtin_amdgcn_sched_barrier(0);
    __builtin_amdgcn_s_barrier();            // safe to overwrite buf[kk&1] next iter
  }
}

// store one C-layout value-pair set into sA[m][k] bf16 via lane-pair exchange.
__device__ __forceinline__ void store_x2_pair_n(const TileCtx& c, u16* sA,
                                                int mt, int n, u32 o01, u32 o23) {
  const bool even = (c.lane & 1) == 0;
  const u32 send = even ? o23 : o01;
  const u32 recv = (u32)__shfl_xor((int)send, 1, 64);
  const u32 hi = even ? recv : o23;
  const u32 lo = even ? o01 : recv;
  const u32 dlo = __builtin_amdgcn_perm(hi, lo, 0x05040100u);
  const u32 dhi = __builtin_amdgcn_perm(hi, lo, 0x07060302u);
  const int np = n & ~1;
  const int mA = mt * 16 + c.quad * 4 + (even ? 0 : 2);
  const int iA = mA * 512 + ((((np >> 3) ^ (mA & 7)) << 3) + (np & 7));
  const int mB = mA + 1;
  const int iB = mB * 512 + ((((np >> 3) ^ (mB & 7)) << 3) + (np & 7));
  *(u32*)&sA[iA] = dlo;
  *(u32*)&sA[iB] = dhi;
}

// LN over 512 cols for 64 rows, 8-wave version. Partials stride 20 floats.
__device__ __forceinline__ void ln_reduce8(const TileCtx& c, float* sRedF,
                                           f32x4 acc[4][4]) {
  #pragma unroll
  for (int mt = 0; mt < 4; ++mt) {
    float rs[4] = {0.f, 0.f, 0.f, 0.f}, rq[4] = {0.f, 0.f, 0.f, 0.f};
    #pragma unroll
    for (int reg = 0; reg < 4; ++reg)
      #pragma unroll
      for (int nt = 0; nt < 4; ++nt) {
        const float gt = acc[mt][nt][reg];
        rs[reg] += gt; rq[reg] += gt * gt;
      }
    #pragma unroll
    for (int msk = 8; msk >= 1; msk >>= 1)
      #pragma unroll
      for (int reg = 0; reg < 4; ++reg) {
        rs[reg] += __shfl_xor(rs[reg], msk, 64);
        rq[reg] += __shfl_xor(rq[reg], msk, 64);
      }
    if (c.col == 0) {
      #pragma unroll
      for (int reg = 0; reg < 4; ++reg) {
        const int m = mt * 16 + c.quad * 4 + reg;
        float2 sq; sq.x = rs[reg]; sq.y = rq[reg];
        *(float2*)&sRedF[m * 20 + c.wid * 2] = sq;
      }
    }
  }
  __syncthreads();
  if (c.tid < 64) {
    const int row = c.tid;
    float s = 0.f, q = 0.f;
    #pragma unroll
    for (int jj = 0; jj < 4; ++jj) {
      float4 v = *(float4*)&sRedF[row * 20 + jj * 4];
      s += v.x + v.z; q += v.y + v.w;
    }
    const float mu = s * (1.0f / H);
    const float rstd = rsqrtf(q * (1.0f / H) - mu * mu + 1e-3f);
    float2 mr; mr.x = mu; mr.y = rstd;
    *(float2*)&sRedF[1280 + row * 2] = mr;
  }
  __syncthreads();
}

// ---------------- vsn_mfma: per-variable GRNs + weighted selection ----------------
__global__ __launch_bounds__(512, 2)
void vsn_mfma(const float* __restrict__ in,     // [MTOT, F]
              const float* __restrict__ w1, const float* __restrict__ b1,
              const float* __restrict__ b2, const float* __restrict__ bg,
              const float* __restrict__ gamma, const float* __restrict__ beta,
              const u16* __restrict__ W2p, const u16* __restrict__ Wgp,
              const float* __restrict__ sel_ws,  // [B, F]
              float* __restrict__ out)           // [MTOT, H]
{
  __shared__ __align__(16) u16 smem[65536];
  u16* const sA  = smem;              // [64][512] bf16 XOR-swizzled, 64 KB
  u16* const sB0 = smem + 32768;      // 32 KB chunk
  u16* const sB1 = smem + 49152;      // 32 KB chunk
  float* const sRedF = (float*)smem;  // LN partials overlay sA (dead there)

  TileCtx c;
  c.tid = threadIdx.x; c.wid = c.tid >> 6; c.lane = c.tid & 63;
  c.quad = c.lane >> 4; c.col = c.lane & 15;
  const int row0 = blockIdx.x * 64;
  const int bidx = row0 >> 7;

  f32x4 outacc[4][4];
  #pragma unroll
  for (int mt = 0; mt < 4; ++mt)
    #pragma unroll
    for (int nt = 0; nt < 4; ++nt) outacc[mt][nt] = (f32x4){0,0,0,0};

  // stage f=0 GEMM1 chunk0 (overlapped by first A1 phase)
  stage_chunk8(c.tid, W2p, sB0);

  #pragma unroll 1
  for (int f = 0; f < NF; ++f) {
    const u16* W2f = W2p + (size_t)f * 262144;
    const u16* Wgf = Wgp + (size_t)f * 262144;
    const u16* W2n = W2p + (size_t)((f + 1) & 3) * 262144;  // next f's GEMM1 (wraps, harmless)

    // A1: sA[m][k] = bf16(elu(v[m]*w1[k] + b1[k])), rotated k-group order
    {
      const int m  = c.tid >> 3;
      const int kb = (c.tid & 7) * 64;
      const float v = in[(size_t)(row0 + m) * NF + f];
      const float* w1f = w1 + f * H;
      const float* b1f = b1 + f * H;
      #pragma unroll
      for (int gg = 0; gg < 8; ++gg) {
        const int ge = (gg + (c.tid & 7)) & 7;
        const int k = kb + ge * 8;
        float4 wv0 = *(const float4*)&w1f[k];
        float4 wv1 = *(const float4*)&w1f[k + 4];
        float4 bv0 = *(const float4*)&b1f[k];
        float4 bv1 = *(const float4*)&b1f[k + 4];
        short8 pk;
        pk[0] = (short)f2bf(elu_f(fmaf(v, wv0.x, bv0.x)));
        pk[1] = (short)f2bf(elu_f(fmaf(v, wv0.y, bv0.y)));
        pk[2] = (short)f2bf(elu_f(fmaf(v, wv0.z, bv0.z)));
        pk[3] = (short)f2bf(elu_f(fmaf(v, wv0.w, bv0.w)));
        pk[4] = (short)f2bf(elu_f(fmaf(v, wv1.x, bv1.x)));
        pk[5] = (short)f2bf(elu_f(fmaf(v, wv1.y, bv1.y)));
        pk[6] = (short)f2bf(elu_f(fmaf(v, wv1.z, bv1.z)));
        pk[7] = (short)f2bf(elu_f(fmaf(v, wv1.w, bv1.w)));
        const int grp = (k >> 3) ^ (m & 7);
        *(short8*)&sA[m * 512 + grp * 8] = pk;
      }
    }
    __syncthreads();   // drains vmcnt -> kloop entry invariant (chunk0 landed)

    f32x4 acc[4][4];
    #pragma unroll
    for (int mt = 0; mt < 4; ++mt)
      #pragma unroll
      for (int nt = 0; nt < 4; ++nt) acc[mt][nt] = (f32x4){0,0,0,0};

    // GEMM1 (tail-prefetches Wgf chunk0 into sB0)
    gemm_kloop8<true>(c, W2f, Wgf, sA, sB0, sB1, acc);

    // epilogue1: x2 = acc + b2 -> packed regs + sA
    u32 x2p[4][4][2];
    {
      float bv[4];
      #pragma unroll
      for (int nt = 0; nt < 4; ++nt) bv[nt] = b2[f * H + c.wid * 64 + nt * 16 + c.col];
      #pragma unroll
      for (int mt = 0; mt < 4; ++mt)
        #pragma unroll
        for (int nt = 0; nt < 4; ++nt) {
          const float x0 = acc[mt][nt][0] + bv[nt];
          const float x1 = acc[mt][nt][1] + bv[nt];
          const float x2 = acc[mt][nt][2] + bv[nt];
          const float x3 = acc[mt][nt][3] + bv[nt];
          const u32 o01 = (u32)f2bf(x0) | ((u32)f2bf(x1) << 16);
          const u32 o23 = (u32)f2bf(x2) | ((u32)f2bf(x3) << 16);
          x2p[mt][nt][0] = o01; x2p[mt][nt][1] = o23;
          store_x2_pair_n(c, sA, mt, c.wid * 64 + nt * 16 + c.col, o01, o23);
        }
    }
    __syncthreads();   // drains GEMM1 tail-prefetch -> GEMM2 entry invariant

    // GEMM2 (tail-prefetches next f's W2 chunk0 -> overlaps gate+LN epilogue)
    #pragma unroll
    for (int mt = 0; mt < 4; ++mt)
      #pragma unroll
      for (int nt = 0; nt < 4; ++nt) acc[mt][nt] = (f32x4){0,0,0,0};
    gemm_kloop8<true>(c, Wgf, W2n, sA, sB0, sB1, acc);

    // gate + LN + weighted accumulate
    {
      const float selw = sel_ws[bidx * NF + f];
      float bv[4];
      #pragma unroll
      for (int nt = 0; nt < 4; ++nt) bv[nt] = bg[f * H + c.wid * 64 + nt * 16 + c.col];
      #pragma unroll
      for (int mt = 0; mt < 4; ++mt) {
        float vr[4];
        #pragma unroll
        for (int reg = 0; reg < 4; ++reg)
          vr[reg] = in[(size_t)(row0 + mt * 16 + c.quad * 4 + reg) * NF + f];
        #pragma unroll
        for (int nt = 0; nt < 4; ++nt)
          #pragma unroll
          for (int reg = 0; reg < 4; ++reg) {
            const u32 w = x2p[mt][nt][reg >> 1];
            const float x2v = bf2f((reg & 1) ? (w >> 16) : (w & 0xffffu));
            const float gv = sigmoid_f(acc[mt][nt][reg] + bv[nt]);
            acc[mt][nt][reg] = gv * x2v + (1.0f - gv) * vr[reg];
          }
      }
      ln_reduce8(c, sRedF, acc);
      float gm[4], bt[4];
      #pragma unroll
      for (int nt = 0; nt < 4; ++nt) {
        const int n = f * H + c.wid * 64 + nt * 16 + c.col;
        gm[nt] = gamma[n]; bt[nt] = beta[n];
      }
      #pragma unroll
      for (int mt = 0; mt < 4; ++mt)
        #pragma unroll
        for (int reg = 0; reg < 4; ++reg) {
          const int m = mt * 16 + c.quad * 4 + reg;
          float2 mr = *(float2*)&sRedF[1280 + m * 2];
          #pragma unroll
          for (int nt = 0; nt < 4; ++nt) {
            const float tv = gm[nt] * ((acc[mt][nt][reg] - mr.x) * mr.y) + bt[nt];
            outacc[mt][nt][reg] = fmaf(selw, tv, outacc[mt][nt][reg]);
          }
        }
      __syncthreads();   // sRedF reads done before next f's A1 overwrites sA
    }
  }

  // store selected [MTOT, H]
  #pragma unroll
  for (int mt = 0; mt < 4; ++mt)
    #pragma unroll
    for (int reg = 0; reg < 4; ++reg) {
      const int m = row0 + mt * 16 + c.quad * 4 + reg;
      #pragma unroll
      for (int nt = 0; nt < 4; ++nt)
        out[(size_t)m * H + c.wid * 64 + nt * 16 + c.col] = outacc[mt][nt][reg];
    }
}

extern "C" void kernel_launch(void* const* d_in, const int* in_sizes, int n_in,
                              void* d_out, int out_size, void* d_ws, size_t ws_size,
                              hipStream_t stream) {
  const float* in_     = (const float*)d_in[0];
  const float* W1c     = (const float*)d_in[1];
  const float* b1c     = (const float*)d_in[2];
  const float* W2c     = (const float*)d_in[3];
  const float* b2c     = (const float*)d_in[4];
  const float* Wgc     = (const float*)d_in[5];
  const float* bgc     = (const float*)d_in[6];
  const float* gamma_c = (const float*)d_in[7];
  const float* beta_c  = (const float*)d_in[8];
  const float* Wsel    = (const float*)d_in[9];
  const float* bsel    = (const float*)d_in[10];
  const float* w1      = (const float*)d_in[11];
  const float* b1v     = (const float*)d_in[12];
  const float* W2      = (const float*)d_in[13];
  const float* b2v     = (const float*)d_in[14];
  const float* Wg      = (const float*)d_in[15];
  const float* bgv     = (const float*)d_in[16];
  const float* gma     = (const float*)d_in[17];
  const float* bta     = (const float*)d_in[18];

  float* out_sel = (float*)d_out;                      // [MTOT, H]
  float* out_w   = (float*)d_out + (size_t)MTOT * H;   // [B, T, 1, F]

  float* sel_ws = (float*)d_ws;                        // 4 KB
  u16*   W2p    = (u16*)((char*)d_ws + 4096);          // 2 MB
  u16*   Wgp    = W2p + (size_t)NF * H * H;            // 2 MB
  u16*   Cp     = Wgp + (size_t)NF * H * H;            // 1.5 MB (W1c|W2c|Wgc)

  hipLaunchKernelGGL(pack_weights, dim3(1408), dim3(256), 0, stream,
                     W2, Wg, W1c, W2c, Wgc, W2p, Wgp, Cp);
  hipLaunchKernelGGL(ctx_mfma, dim3(4), dim3(1024), 0, stream,
                     in_, Cp, b1c, b2c, bgc, gamma_c, beta_c,
                     Wsel, bsel, sel_ws, out_w);
  hipLaunchKernelGGL(vsn_mfma, dim3(MTOT / 64), dim3(512), 0, stream,
                     in_, w1, b1v, b2v, bgv, gma, bta, W2p, Wgp, sel_ws, out_sel);
}

// Round 5
// 511.232 us; speedup vs baseline: 1.1821x; 1.0724x over previous
//
#include <hip/hip_runtime.h>
#include <math.h>

// VariableSelectionNetwork — round 7.
// R6 post-mortem: counted-vmcnt depth-1 + 2 barriers + sched pinning = 406us
// (worse than R4's 346: R4's syncthreads already gave depth-1 cover since
// stage issues at loop top). Corrected model: 1 block/CU (128KB LDS), 2
// waves/SIMD, zero TLP; chunk fetches are HBM-class (L2 thrashed by out/spill
// churn, FETCH ~ 0.5MB/us across rounds); depth-1 leaves ~300+ cyc exposed/kk.
// Fix: PREFETCH DEPTH 2 — 3 chunk buffers (3x32KB) + sA 64KB = 160KB LDS
// (the whole pool; occupancy unchanged). Per kk:
//   stage chunk c+2 -> buf[(c+2)%3]; vmcnt(8); BAR; [ds+MFMA, compiler-
//   scheduled, setprio]; sched_barrier(0); BAR.
// Uniform 4-glld/iter (tails wrap to next GEMM chunk0/1; last wrap is dead).
// Write-safety: buf[(c+2)%3] last read at c-1, end-of-(c-1) BAR precedes.
// Read-safety: per-wave vmcnt(8) then BAR. Same pipeline in ctx (vmcnt(4)).
// Side: nontemporal out stores (less L2 pollution -> weights stay resident).

#define H 512
#define NF 4
#define MTOT 32768

typedef unsigned short u16;
typedef unsigned int u32;
typedef __attribute__((ext_vector_type(8))) short short8;   // 8 bf16 = 4 VGPRs
typedef __attribute__((ext_vector_type(4))) float f32x4;    // MFMA C/D

__device__ __forceinline__ u16 f2bf(float x) {
  union { float f; u32 u; } v; v.f = x;
  return (u16)((v.u + 0x7fffu + ((v.u >> 16) & 1u)) >> 16);  // RNE
}
__device__ __forceinline__ float bf2f(u32 h16) {
  union { u32 u; float f; } v; v.u = h16 << 16;
  return v.f;
}
__device__ __forceinline__ float elu_f(float x) {
  return x > 0.0f ? x : (__expf(x) - 1.0f);
}
__device__ __forceinline__ float sigmoid_f(float x) {
  return __builtin_amdgcn_rcpf(1.0f + __expf(-x));
}

// async global->LDS, 16B per lane; LDS dest = wave-uniform base + lane*16.
__device__ __forceinline__ void glld16(const void* g, void* l) {
  __builtin_amdgcn_global_load_lds(
      (const __attribute__((address_space(1))) u32*)(unsigned long long)(uintptr_t)g,
      (__attribute__((address_space(3))) u32*)(u32)(uintptr_t)l, 16, 0, 0);
}

#define MFMA16(a, b, c) __builtin_amdgcn_mfma_f32_16x16x32_bf16((a), (b), (c), 0, 0, 0)

// ---------------- pack_weights: fp32 -> bf16 B-fragment-major ----------------
// Packed per matrix: (((kk*32 + ntg)*64 + lane)*8 + j); chunk kk = 32k x 512n
// = 32KB contiguous. mats 0-3 W2[f], 4-7 Wg[f], 8 W1c, 9 W2c, 10 Wgc.
__global__ __launch_bounds__(256)
void pack_weights(const float* __restrict__ W2, const float* __restrict__ Wg,
                  const float* __restrict__ W1c, const float* __restrict__ W2c,
                  const float* __restrict__ Wgc,
                  u16* __restrict__ W2p, u16* __restrict__ Wgp, u16* __restrict__ Cp) {
  int g = blockIdx.x * 256 + threadIdx.x;       // 0 .. 11*32768-1
  int r = g & 32767; int mat = g >> 15;
  if (mat >= 11) return;
  int lane = r & 63, nt = (r >> 6) & 31, kk = (r >> 11) & 15;
  const float* src; u16* dst;
  if (mat < 4)      { src = W2 + (size_t)mat * 262144;       dst = W2p + (size_t)mat * 262144; }
  else if (mat < 8) { src = Wg + (size_t)(mat - 4) * 262144; dst = Wgp + (size_t)(mat - 4) * 262144; }
  else              { src = (mat == 8 ? W1c : (mat == 9 ? W2c : Wgc));
                      dst = Cp + (size_t)(mat - 8) * 262144; }
  dst += (((size_t)kk * 32 + nt) * 64 + lane) * 8;
  int n  = nt * 16 + (lane & 15);
  int k0 = kk * 32 + (lane >> 4) * 8;
  short8 pk;
  #pragma unroll
  for (int j = 0; j < 8; ++j) pk[j] = (short)f2bf(src[(size_t)(k0 + j) * H + n]);
  *(short8*)dst = pk;
}

struct TileCtx {
  int tid, wid, lane, quad, col;
};

// ======================= 16-wave machinery (ctx_mfma) =======================
// Block: 1024 thr = 16 waves. M-tile 64 rows. Wave wid owns cols wid*32..+31.
// sA: 64KB bf16 XOR-swizzled. sB: 3 x 32KB chunk buffers, depth-2 pipeline.

__device__ __forceinline__ void stage_chunk16(int tid, const u16* src, u16* dst) {
  glld16(src + tid * 8, dst + tid * 8);
  glld16(src + tid * 8 + 8192, dst + tid * 8 + 8192);
}

// rot = buffer index of this GEMM's chunk0 (advances +1 mod 3 per GEMM).
// Wnext: next GEMM in the chunk sequence (kk=14 stages its chunk0, kk=15 its
// chunk1). Last GEMM wraps harmlessly.
__device__ __forceinline__ void gemm_kloop(const TileCtx& c, const u16* Wp,
                                           const u16* Wnext,
                                           u16* sA, u16* sBb, int rot,
                                           f32x4 acc[4][2]) {
  int rb = rot;
  int wb = rot + 2; if (wb >= 3) wb -= 3;
  #pragma unroll 1
  for (int kk = 0; kk < 16; ++kk) {
    const u16* src = (kk < 14) ? (Wp + (kk + 2) * 16384)
                               : (Wnext + (kk - 14) * 16384);
    stage_chunk16(c.tid, src, sBb + wb * 16384);
    asm volatile("s_waitcnt vmcnt(4)" ::: "memory");   // chunk kk landed (own)
    __builtin_amdgcn_s_barrier();                      // ...for all waves
    __builtin_amdgcn_sched_barrier(0);
    const u16* bp = sBb + rb * 16384 + c.wid * 1024 + c.lane * 8;
    short8 bb0 = *(const short8*)(bp);
    short8 bb1 = *(const short8*)(bp + 512);
    const int kq = kk * 4 + c.quad;
    const int s0 = (kq ^ (c.col & 7)) * 8;
    short8 a0 = *(const short8*)&sA[(     c.col) * 512 + s0];
    short8 a1 = *(const short8*)&sA[(16 + c.col) * 512 + s0];
    short8 a2 = *(const short8*)&sA[(32 + c.col) * 512 + s0];
    short8 a3 = *(const short8*)&sA[(48 + c.col) * 512 + s0];
    __builtin_amdgcn_s_setprio(1);
    acc[0][0] = MFMA16(a0, bb0, acc[0][0]); acc[0][1] = MFMA16(a0, bb1, acc[0][1]);
    acc[1][0] = MFMA16(a1, bb0, acc[1][0]); acc[1][1] = MFMA16(a1, bb1, acc[1][1]);
    acc[2][0] = MFMA16(a2, bb0, acc[2][0]); acc[2][1] = MFMA16(a2, bb1, acc[2][1]);
    acc[3][0] = MFMA16(a3, bb0, acc[3][0]); acc[3][1] = MFMA16(a3, bb1, acc[3][1]);
    __builtin_amdgcn_s_setprio(0);
    __builtin_amdgcn_sched_barrier(0);   // keep next iter's glld below this BAR
    __builtin_amdgcn_s_barrier();        // everyone done reading buf rb
    ++rb; if (rb == 3) rb = 0;
    ++wb; if (wb == 3) wb = 0;
  }
}

__device__ __forceinline__ void store_x2_pair(const TileCtx& c, u16* sA,
                                              int mt, int nt, u32 o01, u32 o23) {
  const bool even = (c.lane & 1) == 0;
  const u32 send = even ? o23 : o01;
  const u32 recv = (u32)__shfl_xor((int)send, 1, 64);
  const u32 hi = even ? recv : o23;
  const u32 lo = even ? o01 : recv;
  const u32 dlo = __builtin_amdgcn_perm(hi, lo, 0x05040100u);
  const u32 dhi = __builtin_amdgcn_perm(hi, lo, 0x07060302u);
  const int n  = c.wid * 32 + nt * 16 + c.col;
  const int np = n & ~1;
  const int mA = mt * 16 + c.quad * 4 + (even ? 0 : 2);
  const int iA = mA * 512 + ((((np >> 3) ^ (mA & 7)) << 3) + (np & 7));
  const int mB = mA + 1;
  const int iB = mB * 512 + ((((np >> 3) ^ (mB & 7)) << 3) + (np & 7));
  *(u32*)&sA[iA] = dlo;
  *(u32*)&sA[iB] = dhi;
}

__device__ __forceinline__ void ln_reduce(const TileCtx& c, float* sRedF,
                                          f32x4 acc[4][2]) {
  #pragma unroll
  for (int mt = 0; mt < 4; ++mt) {
    float rs[4] = {0.f, 0.f, 0.f, 0.f}, rq[4] = {0.f, 0.f, 0.f, 0.f};
    #pragma unroll
    for (int reg = 0; reg < 4; ++reg)
      #pragma unroll
      for (int nt = 0; nt < 2; ++nt) {
        const float gt = acc[mt][nt][reg];
        rs[reg] += gt; rq[reg] += gt * gt;
      }
    #pragma unroll
    for (int msk = 8; msk >= 1; msk >>= 1)
      #pragma unroll
      for (int reg = 0; reg < 4; ++reg) {
        rs[reg] += __shfl_xor(rs[reg], msk, 64);
        rq[reg] += __shfl_xor(rq[reg], msk, 64);
      }
    if (c.col == 0) {
      #pragma unroll
      for (int reg = 0; reg < 4; ++reg) {
        const int m = mt * 16 + c.quad * 4 + reg;
        float2 sq; sq.x = rs[reg]; sq.y = rq[reg];
        *(float2*)&sRedF[m * 36 + c.wid * 2] = sq;
      }
    }
  }
  __syncthreads();
  if (c.tid < 64) {
    const int row = c.tid;
    float s = 0.f, q = 0.f;
    #pragma unroll
    for (int jj = 0; jj < 8; ++jj) {
      float4 v = *(float4*)&sRedF[row * 36 + jj * 4];
      s += v.x + v.z; q += v.y + v.w;
    }
    const float mu = s * (1.0f / H);
    const float rstd = rsqrtf(q * (1.0f / H) - mu * mu + 1e-3f);
    float2 mr; mr.x = mu; mr.y = rstd;
    *(float2*)&sRedF[2304 + row * 2] = mr;
  }
  __syncthreads();
}

// ---------------- ctx GRN as MFMA: 4 blocks x 64 batch rows ----------------
__global__ __launch_bounds__(1024)
void ctx_mfma(const float* __restrict__ in,       // [B, 512] flat
              const u16* __restrict__ Cp,         // W1cp | W2cp | Wgcp
              const float* __restrict__ b1c, const float* __restrict__ b2c,
              const float* __restrict__ bgc,
              const float* __restrict__ gamma_c, const float* __restrict__ beta_c,
              const float* __restrict__ Wsel, const float* __restrict__ bsel,
              float* __restrict__ sel_ws,         // [B, F]
              float* __restrict__ selw_out)       // [B, T, 1, F]
{
  __shared__ __align__(16) u16 smem[81920];       // 160KB: sA 64K + 3x32K
  u16* const sA  = smem;
  u16* const sBb = smem + 32768;                  // 3 chunk buffers
  float* const sRedF = (float*)smem;              // LN partials overlay sA
  float* const sZ   = (float*)sBb;                // [256][4] logit partials
  float* const sSel = (float*)sBb + 1024;         // [64][4] softmax

  TileCtx c;
  c.tid = threadIdx.x; c.wid = c.tid >> 6; c.lane = c.tid & 63;
  c.quad = c.lane >> 4; c.col = c.lane & 15;
  const int b0 = blockIdx.x * 64;
  const u16* W1cp = Cp;
  const u16* W2cp = Cp + 262144;
  const u16* Wgcp = Cp + 524288;

  // prologue: stage W1c chunk0 -> buf0, chunk1 -> buf1
  stage_chunk16(c.tid, W1cp, sBb);
  stage_chunk16(c.tid, W1cp + 16384, sBb + 16384);

  // A0: flat -> sA bf16 (rotated k-group order to spread LDS write banks)
  {
    const int m = c.tid >> 4;
    const int kb = (c.tid & 15) * 32;
    const float* rowp = in + (size_t)(b0 + m) * H;
    #pragma unroll
    for (int gg = 0; gg < 4; ++gg) {
      const int ge = (gg + (c.tid & 15)) & 3;
      const int k = kb + ge * 8;
      float4 v0 = *(const float4*)&rowp[k];
      float4 v1 = *(const float4*)&rowp[k + 4];
      short8 pk;
      pk[0] = (short)f2bf(v0.x); pk[1] = (short)f2bf(v0.y);
      pk[2] = (short)f2bf(v0.z); pk[3] = (short)f2bf(v0.w);
      pk[4] = (short)f2bf(v1.x); pk[5] = (short)f2bf(v1.y);
      pk[6] = (short)f2bf(v1.z); pk[7] = (short)f2bf(v1.w);
      const int grp = (k >> 3) ^ (m & 7);
      *(short8*)&sA[m * 512 + grp * 8] = pk;
    }
  }
  __syncthreads();   // drains vmcnt (chunks 0,1 in LDS) -> kloop invariant

  f32x4 acc[4][2];
  #pragma unroll
  for (int mt = 0; mt < 4; ++mt) { acc[mt][0] = (f32x4){0,0,0,0}; acc[mt][1] = (f32x4){0,0,0,0}; }

  // GEMM1: x1 = elu(flat@W1c + b1c) -> sA    (rot 0)
  gemm_kloop(c, W1cp, W2cp, sA, sBb, 0, acc);
  {
    float bv[2] = { b1c[c.wid * 32 + c.col], b1c[c.wid * 32 + 16 + c.col] };
    #pragma unroll
    for (int mt = 0; mt < 4; ++mt)
      #pragma unroll
      for (int nt = 0; nt < 2; ++nt) {
        const float x0 = elu_f(acc[mt][nt][0] + bv[nt]);
        const float x1 = elu_f(acc[mt][nt][1] + bv[nt]);
        const float x2 = elu_f(acc[mt][nt][2] + bv[nt]);
        const float x3 = elu_f(acc[mt][nt][3] + bv[nt]);
        store_x2_pair(c, sA, mt, nt,
                      (u32)f2bf(x0) | ((u32)f2bf(x1) << 16),
                      (u32)f2bf(x2) | ((u32)f2bf(x3) << 16));
      }
  }
  __syncthreads();

  // GEMM2: x = x1@W2c + b2c (keep fp32 in regs, also -> sA)   (rot 1)
  float xr[4][2][4];
  #pragma unroll
  for (int mt = 0; mt < 4; ++mt) { acc[mt][0] = (f32x4){0,0,0,0}; acc[mt][1] = (f32x4){0,0,0,0}; }
  gemm_kloop(c, W2cp, Wgcp, sA, sBb, 1, acc);
  {
    float bv[2] = { b2c[c.wid * 32 + c.col], b2c[c.wid * 32 + 16 + c.col] };
    #pragma unroll
    for (int mt = 0; mt < 4; ++mt)
      #pragma unroll
      for (int nt = 0; nt < 2; ++nt) {
        #pragma unroll
        for (int reg = 0; reg < 4; ++reg) xr[mt][nt][reg] = acc[mt][nt][reg] + bv[nt];
        store_x2_pair(c, sA, mt, nt,
                      (u32)f2bf(xr[mt][nt][0]) | ((u32)f2bf(xr[mt][nt][1]) << 16),
                      (u32)f2bf(xr[mt][nt][2]) | ((u32)f2bf(xr[mt][nt][3]) << 16));
      }
  }
  __syncthreads();

  // GEMM3: gpre = x@Wgc; gate + skip + LN -> ctx   (rot 2; next wraps to W1c)
  #pragma unroll
  for (int mt = 0; mt < 4; ++mt) { acc[mt][0] = (f32x4){0,0,0,0}; acc[mt][1] = (f32x4){0,0,0,0}; }
  gemm_kloop(c, Wgcp, W1cp, sA, sBb, 2, acc);
  {
    float bv[2] = { bgc[c.wid * 32 + c.col], bgc[c.wid * 32 + 16 + c.col] };
    #pragma unroll
    for (int mt = 0; mt < 4; ++mt)
      #pragma unroll
      for (int nt = 0; nt < 2; ++nt) {
        const int n = c.wid * 32 + nt * 16 + c.col;
        #pragma unroll
        for (int reg = 0; reg < 4; ++reg) {
          const int m = mt * 16 + c.quad * 4 + reg;
          const float fl = in[(size_t)(b0 + m) * H + n];
          const float gv = sigmoid_f(acc[mt][nt][reg] + bv[nt]);
          acc[mt][nt][reg] = gv * xr[mt][nt][reg] + (1.0f - gv) * fl;
        }
      }
  }
  ln_reduce(c, sRedF, acc);   // overlays sA; sA re-written below after LN
  // ctx -> sA (plain [m][n] bf16 layout) for the sel dot
  {
    float gm[2], bt[2];
    #pragma unroll
    for (int nt = 0; nt < 2; ++nt) {
      const int n = c.wid * 32 + nt * 16 + c.col;
      gm[nt] = gamma_c[n]; bt[nt] = beta_c[n];
    }
    u16 cv[4][2][4];
    #pragma unroll
    for (int mt = 0; mt < 4; ++mt)
      #pragma unroll
      for (int reg = 0; reg < 4; ++reg) {
        const int m = mt * 16 + c.quad * 4 + reg;
        float2 mr = *(float2*)&sRedF[2304 + m * 2];
        #pragma unroll
        for (int nt = 0; nt < 2; ++nt)
          cv[mt][nt][reg] = f2bf(gm[nt] * ((acc[mt][nt][reg] - mr.x) * mr.y) + bt[nt]);
      }
    __syncthreads();   // sRedF reads done; sA region reusable
    #pragma unroll
    for (int mt = 0; mt < 4; ++mt)
      #pragma unroll
      for (int reg = 0; reg < 4; ++reg) {
        const int m = mt * 16 + c.quad * 4 + reg;
        #pragma unroll
        for (int nt = 0; nt < 2; ++nt)
          sA[m * 512 + c.wid * 32 + nt * 16 + c.col] = cv[mt][nt][reg];
      }
  }
  __syncthreads();

  // sel logits: all 1024 threads, (row, f, quarter): each dots 128 h
  {
    const int r = c.tid >> 4, fq = (c.tid >> 2) & 3, p = c.tid & 3;
    float z = 0.f;
    const u16* rowp = &sA[r * 512 + p * 128];
    const float* wp = Wsel + (size_t)p * 128 * NF + fq;
    #pragma unroll 8
    for (int h = 0; h < 128; ++h) z += bf2f(rowp[h]) * wp[h * NF];
    sZ[((r * 4 + fq) << 2) + p] = z;
  }
  __syncthreads();
  if (c.tid < 64) {
    const int r = c.tid;
    float zz[4];
    #pragma unroll
    for (int ff = 0; ff < 4; ++ff) {
      float4 v = *(float4*)&sZ[(r * 4 + ff) << 2];
      zz[ff] = v.x + v.y + v.z + v.w + bsel[ff];
    }
    float mx = fmaxf(fmaxf(zz[0], zz[1]), fmaxf(zz[2], zz[3]));
    float e0 = __expf(zz[0]-mx), e1 = __expf(zz[1]-mx), e2 = __expf(zz[2]-mx), e3 = __expf(zz[3]-mx);
    float inv = __builtin_amdgcn_rcpf(e0 + e1 + e2 + e3);
    sSel[r*4]   = e0*inv; sSel[r*4+1] = e1*inv;
    sSel[r*4+2] = e2*inv; sSel[r*4+3] = e3*inv;
  }
  __syncthreads();
  if (c.tid < 256) {
    const int r = c.tid >> 2, f = c.tid & 3;
    sel_ws[(b0 + r) * NF + f] = sSel[r * 4 + f];
  }
  {
    const int m = c.tid >> 4;
    const int jb = (c.tid & 15) * 32;
    float s0 = sSel[m*4], s1 = sSel[m*4+1], s2 = sSel[m*4+2], s3 = sSel[m*4+3];
    float4 v; v.x = s0; v.y = s1; v.z = s2; v.w = s3;
    #pragma unroll
    for (int j = 0; j < 8; ++j)
      *(float4*)&selw_out[(size_t)(b0 + m) * H + jb + j * 4] = v;
  }
}

// ======================= 8-wave machinery (vsn_mfma) =======================
// Block: 512 thr = 8 waves. M-tile 64 rows. Wave wid owns cols wid*64..+63.
// Per-thread frags: mt=4, nt=4 -> 16 MFMA per 8 ds_read_b128. Depth-2
// pipeline over 3 chunk buffers; chunk sequence W2[0],Wg[0],...,Wg[3].

__device__ __forceinline__ void stage_chunk8(int tid, const u16* src, u16* dst) {
  glld16(src + tid * 8,         dst + tid * 8);
  glld16(src + tid * 8 + 4096,  dst + tid * 8 + 4096);
  glld16(src + tid * 8 + 8192,  dst + tid * 8 + 8192);
  glld16(src + tid * 8 + 12288, dst + tid * 8 + 12288);
}

__device__ __forceinline__ void gemm_kloop8(const TileCtx& c, const u16* Wp,
                                            const u16* Wnext,
                                            u16* sA, u16* sBb, int rot,
                                            f32x4 acc[4][4]) {
  int rb = rot;
  int wb = rot + 2; if (wb >= 3) wb -= 3;
  #pragma unroll 1
  for (int kk = 0; kk < 16; ++kk) {
    const u16* src = (kk < 14) ? (Wp + (kk + 2) * 16384)
                               : (Wnext + (kk - 14) * 16384);
    stage_chunk8(c.tid, src, sBb + wb * 16384);
    asm volatile("s_waitcnt vmcnt(8)" ::: "memory");   // chunk kk landed (own)
    __builtin_amdgcn_s_barrier();                      // ...for all waves
    __builtin_amdgcn_sched_barrier(0);
    const u16* bp = sBb + rb * 16384 + c.wid * 2048 + c.lane * 8;
    short8 bb[4];
    #pragma unroll
    for (int nt = 0; nt < 4; ++nt) bb[nt] = *(const short8*)(bp + nt * 512);
    const int kq = kk * 4 + c.quad;
    const int s0 = (kq ^ (c.col & 7)) * 8;
    short8 a0 = *(const short8*)&sA[(     c.col) * 512 + s0];
    short8 a1 = *(const short8*)&sA[(16 + c.col) * 512 + s0];
    short8 a2 = *(const short8*)&sA[(32 + c.col) * 512 + s0];
    short8 a3 = *(const short8*)&sA[(48 + c.col) * 512 + s0];
    __builtin_amdgcn_s_setprio(1);
    #pragma unroll
    for (int nt = 0; nt < 4; ++nt) acc[0][nt] = MFMA16(a0, bb[nt], acc[0][nt]);
    #pragma unroll
    for (int nt = 0; nt < 4; ++nt) acc[1][nt] = MFMA16(a1, bb[nt], acc[1][nt]);
    #pragma unroll
    for (int nt = 0; nt < 4; ++nt) acc[2][nt] = MFMA16(a2, bb[nt], acc[2][nt]);
    #pragma unroll
    for (int nt = 0; nt < 4; ++nt) acc[3][nt] = MFMA16(a3, bb[nt], acc[3][nt]);
    __builtin_amdgcn_s_setprio(0);
    __builtin_amdgcn_sched_barrier(0);   // keep next iter's glld below this BAR
    __builtin_amdgcn_s_barrier();        // everyone done reading buf rb
    ++rb; if (rb == 3) rb = 0;
    ++wb; if (wb == 3) wb = 0;
  }
}

// store one C-layout value-pair set into sA[m][k] bf16 via lane-pair exchange.
__device__ __forceinline__ void store_x2_pair_n(const TileCtx& c, u16* sA,
                                                int mt, int n, u32 o01, u32 o23) {
  const bool even = (c.lane & 1) == 0;
  const u32 send = even ? o23 : o01;
  const u32 recv = (u32)__shfl_xor((int)send, 1, 64);
  const u32 hi = even ? recv : o23;
  const u32 lo = even ? o01 : recv;
  const u32 dlo = __builtin_amdgcn_perm(hi, lo, 0x05040100u);
  const u32 dhi = __builtin_amdgcn_perm(hi, lo, 0x07060302u);
  const int np = n & ~1;
  const int mA = mt * 16 + c.quad * 4 + (even ? 0 : 2);
  const int iA = mA * 512 + ((((np >> 3) ^ (mA & 7)) << 3) + (np & 7));
  const int mB = mA + 1;
  const int iB = mB * 512 + ((((np >> 3) ^ (mB & 7)) << 3) + (np & 7));
  *(u32*)&sA[iA] = dlo;
  *(u32*)&sA[iB] = dhi;
}

// LN over 512 cols for 64 rows, 8-wave version. Partials stride 20 floats.
__device__ __forceinline__ void ln_reduce8(const TileCtx& c, float* sRedF,
                                           f32x4 acc[4][4]) {
  #pragma unroll
  for (int mt = 0; mt < 4; ++mt) {
    float rs[4] = {0.f, 0.f, 0.f, 0.f}, rq[4] = {0.f, 0.f, 0.f, 0.f};
    #pragma unroll
    for (int reg = 0; reg < 4; ++reg)
      #pragma unroll
      for (int nt = 0; nt < 4; ++nt) {
        const float gt = acc[mt][nt][reg];
        rs[reg] += gt; rq[reg] += gt * gt;
      }
    #pragma unroll
    for (int msk = 8; msk >= 1; msk >>= 1)
      #pragma unroll
      for (int reg = 0; reg < 4; ++reg) {
        rs[reg] += __shfl_xor(rs[reg], msk, 64);
        rq[reg] += __shfl_xor(rq[reg], msk, 64);
      }
    if (c.col == 0) {
      #pragma unroll
      for (int reg = 0; reg < 4; ++reg) {
        const int m = mt * 16 + c.quad * 4 + reg;
        float2 sq; sq.x = rs[reg]; sq.y = rq[reg];
        *(float2*)&sRedF[m * 20 + c.wid * 2] = sq;
      }
    }
  }
  __syncthreads();
  if (c.tid < 64) {
    const int row = c.tid;
    float s = 0.f, q = 0.f;
    #pragma unroll
    for (int jj = 0; jj < 4; ++jj) {
      float4 v = *(float4*)&sRedF[row * 20 + jj * 4];
      s += v.x + v.z; q += v.y + v.w;
    }
    const float mu = s * (1.0f / H);
    const float rstd = rsqrtf(q * (1.0f / H) - mu * mu + 1e-3f);
    float2 mr; mr.x = mu; mr.y = rstd;
    *(float2*)&sRedF[1280 + row * 2] = mr;
  }
  __syncthreads();
}

// ---------------- vsn_mfma: per-variable GRNs + weighted selection ----------------
__global__ __launch_bounds__(512, 2)
void vsn_mfma(const float* __restrict__ in,     // [MTOT, F]
              const float* __restrict__ w1, const float* __restrict__ b1,
              const float* __restrict__ b2, const float* __restrict__ bg,
              const float* __restrict__ gamma, const float* __restrict__ beta,
              const u16* __restrict__ W2p, const u16* __restrict__ Wgp,
              const float* __restrict__ sel_ws,  // [B, F]
              float* __restrict__ out)           // [MTOT, H]
{
  __shared__ __align__(16) u16 smem[81920];     // 160KB: sA 64K + 3x32K
  u16* const sA  = smem;                        // [64][512] bf16 XOR-swizzled
  u16* const sBb = smem + 32768;                // 3 chunk buffers
  float* const sRedF = (float*)smem;            // LN partials overlay sA

  TileCtx c;
  c.tid = threadIdx.x; c.wid = c.tid >> 6; c.lane = c.tid & 63;
  c.quad = c.lane >> 4; c.col = c.lane & 15;
  const int row0 = blockIdx.x * 64;
  const int bidx = row0 >> 7;

  f32x4 outacc[4][4];
  #pragma unroll
  for (int mt = 0; mt < 4; ++mt)
    #pragma unroll
    for (int nt = 0; nt < 4; ++nt) outacc[mt][nt] = (f32x4){0,0,0,0};

  // prologue: stage W2[0] chunk0 -> buf0, chunk1 -> buf1
  stage_chunk8(c.tid, W2p, sBb);
  stage_chunk8(c.tid, W2p + 16384, sBb + 16384);

  int rot = 0;   // buffer index of the next GEMM's chunk0 (advances +1 mod 3)

  #pragma unroll 1
  for (int f = 0; f < NF; ++f) {
    const u16* W2f = W2p + (size_t)f * 262144;
    const u16* Wgf = Wgp + (size_t)f * 262144;
    const u16* W2n = W2p + (size_t)((f + 1) & 3) * 262144;  // wraps; last is dead

    // A1: sA[m][k] = bf16(elu(v[m]*w1[k] + b1[k])), rotated k-group order
    {
      const int m  = c.tid >> 3;
      const int kb = (c.tid & 7) * 64;
      const float v = in[(size_t)(row0 + m) * NF + f];
      const float* w1f = w1 + f * H;
      const float* b1f = b1 + f * H;
      #pragma unroll
      for (int gg = 0; gg < 8; ++gg) {
        const int ge = (gg + (c.tid & 7)) & 7;
        const int k = kb + ge * 8;
        float4 wv0 = *(const float4*)&w1f[k];
        float4 wv1 = *(const float4*)&w1f[k + 4];
        float4 bv0 = *(const float4*)&b1f[k];
        float4 bv1 = *(const float4*)&b1f[k + 4];
        short8 pk;
        pk[0] = (short)f2bf(elu_f(fmaf(v, wv0.x, bv0.x)));
        pk[1] = (short)f2bf(elu_f(fmaf(v, wv0.y, bv0.y)));
        pk[2] = (short)f2bf(elu_f(fmaf(v, wv0.z, bv0.z)));
        pk[3] = (short)f2bf(elu_f(fmaf(v, wv0.w, bv0.w)));
        pk[4] = (short)f2bf(elu_f(fmaf(v, wv1.x, bv1.x)));
        pk[5] = (short)f2bf(elu_f(fmaf(v, wv1.y, bv1.y)));
        pk[6] = (short)f2bf(elu_f(fmaf(v, wv1.z, bv1.z)));
        pk[7] = (short)f2bf(elu_f(fmaf(v, wv1.w, bv1.w)));
        const int grp = (k >> 3) ^ (m & 7);
        *(short8*)&sA[m * 512 + grp * 8] = pk;
      }
    }
    __syncthreads();   // drains vmcnt -> chunks 0,1 of GEMM1 in LDS

    f32x4 acc[4][4];
    #pragma unroll
    for (int mt = 0; mt < 4; ++mt)
      #pragma unroll
      for (int nt = 0; nt < 4; ++nt) acc[mt][nt] = (f32x4){0,0,0,0};

    // GEMM1 (tail stages Wgf chunks 0,1)
    gemm_kloop8(c, W2f, Wgf, sA, sBb, rot, acc);
    rot = (rot + 1) % 3;

    // epilogue1: x2 = acc + b2 -> packed regs + sA
    u32 x2p[4][4][2];
    {
      float bv[4];
      #pragma unroll
      for (int nt = 0; nt < 4; ++nt) bv[nt] = b2[f * H + c.wid * 64 + nt * 16 + c.col];
      #pragma unroll
      for (int mt = 0; mt < 4; ++mt)
        #pragma unroll
        for (int nt = 0; nt < 4; ++nt) {
          const float x0 = acc[mt][nt][0] + bv[nt];
          const float x1 = acc[mt][nt][1] + bv[nt];
          const float x2 = acc[mt][nt][2] + bv[nt];
          const float x3 = acc[mt][nt][3] + bv[nt];
          const u32 o01 = (u32)f2bf(x0) | ((u32)f2bf(x1) << 16);
          const u32 o23 = (u32)f2bf(x2) | ((u32)f2bf(x3) << 16);
          x2p[mt][nt][0] = o01; x2p[mt][nt][1] = o23;
          store_x2_pair_n(c, sA, mt, c.wid * 64 + nt * 16 + c.col, o01, o23);
        }
    }
    __syncthreads();   // drains tail-prefetch -> GEMM2 chunks 0,1 in LDS

    // GEMM2 (tail stages next f's W2 chunks 0,1)
    #pragma unroll
    for (int mt = 0; mt < 4; ++mt)
      #pragma unroll
      for (int nt = 0; nt < 4; ++nt) acc[mt][nt] = (f32x4){0,0,0,0};
    gemm_kloop8(c, Wgf, W2n, sA, sBb, rot, acc);
    rot = (rot + 1) % 3;

    // gate + LN + weighted accumulate
    {
      const float selw = sel_ws[bidx * NF + f];
      float bv[4];
      #pragma unroll
      for (int nt = 0; nt < 4; ++nt) bv[nt] = bg[f * H + c.wid * 64 + nt * 16 + c.col];
      #pragma unroll
      for (int mt = 0; mt < 4; ++mt) {
        float vr[4];
        #pragma unroll
        for (int reg = 0; reg < 4; ++reg)
          vr[reg] = in[(size_t)(row0 + mt * 16 + c.quad * 4 + reg) * NF + f];
        #pragma unroll
        for (int nt = 0; nt < 4; ++nt)
          #pragma unroll
          for (int reg = 0; reg < 4; ++reg) {
            const u32 w = x2p[mt][nt][reg >> 1];
            const float x2v = bf2f((reg & 1) ? (w >> 16) : (w & 0xffffu));
            const float gv = sigmoid_f(acc[mt][nt][reg] + bv[nt]);
            acc[mt][nt][reg] = gv * x2v + (1.0f - gv) * vr[reg];
          }
      }
      ln_reduce8(c, sRedF, acc);
      float gm[4], bt[4];
      #pragma unroll
      for (int nt = 0; nt < 4; ++nt) {
        const int n = f * H + c.wid * 64 + nt * 16 + c.col;
        gm[nt] = gamma[n]; bt[nt] = beta[n];
      }
      #pragma unroll
      for (int mt = 0; mt < 4; ++mt)
        #pragma unroll
        for (int reg = 0; reg < 4; ++reg) {
          const int m = mt * 16 + c.quad * 4 + reg;
          float2 mr = *(float2*)&sRedF[1280 + m * 2];
          #pragma unroll
          for (int nt = 0; nt < 4; ++nt) {
            const float tv = gm[nt] * ((acc[mt][nt][reg] - mr.x) * mr.y) + bt[nt];
            outacc[mt][nt][reg] = fmaf(selw, tv, outacc[mt][nt][reg]);
          }
        }
      __syncthreads();   // sRedF reads done before next f's A1 overwrites sA
    }
  }

  // store selected [MTOT, H] — nontemporal (bypass L2, keep weights resident)
  #pragma unroll
  for (int mt = 0; mt < 4; ++mt)
    #pragma unroll
    for (int reg = 0; reg < 4; ++reg) {
      const int m = row0 + mt * 16 + c.quad * 4 + reg;
      #pragma unroll
      for (int nt = 0; nt < 4; ++nt)
        __builtin_nontemporal_store(outacc[mt][nt][reg],
                                    &out[(size_t)m * H + c.wid * 64 + nt * 16 + c.col]);
    }
}

extern "C" void kernel_launch(void* const* d_in, const int* in_sizes, int n_in,
                              void* d_out, int out_size, void* d_ws, size_t ws_size,
                              hipStream_t stream) {
  const float* in_     = (const float*)d_in[0];
  const float* W1c     = (const float*)d_in[1];
  const float* b1c     = (const float*)d_in[2];
  const float* W2c     = (const float*)d_in[3];
  const float* b2c     = (const float*)d_in[4];
  const float* Wgc     = (const float*)d_in[5];
  const float* bgc     = (const float*)d_in[6];
  const float* gamma_c = (const float*)d_in[7];
  const float* beta_c  = (const float*)d_in[8];
  const float* Wsel    = (const float*)d_in[9];
  const float* bsel    = (const float*)d_in[10];
  const float* w1      = (const float*)d_in[11];
  const float* b1v     = (const float*)d_in[12];
  const float* W2      = (const float*)d_in[13];
  const float* b2v     = (const float*)d_in[14];
  const float* Wg      = (const float*)d_in[15];
  const float* bgv     = (const float*)d_in[16];
  const float* gma     = (const float*)d_in[17];
  const float* bta     = (const float*)d_in[18];

  float* out_sel = (float*)d_out;                      // [MTOT, H]
  float* out_w   = (float*)d_out + (size_t)MTOT * H;   // [B, T, 1, F]

  float* sel_ws = (float*)d_ws;                        // 4 KB
  u16*   W2p    = (u16*)((char*)d_ws + 4096);          // 2 MB
  u16*   Wgp    = W2p + (size_t)NF * H * H;            // 2 MB
  u16*   Cp     = Wgp + (size_t)NF * H * H;            // 1.5 MB (W1c|W2c|Wgc)

  hipLaunchKernelGGL(pack_weights, dim3(1408), dim3(256), 0, stream,
                     W2, Wg, W1c, W2c, Wgc, W2p, Wgp, Cp);
  hipLaunchKernelGGL(ctx_mfma, dim3(4), dim3(1024), 0, stream,
                     in_, Cp, b1c, b2c, bgc, gamma_c, beta_c,
                     Wsel, bsel, sel_ws, out_w);
  hipLaunchKernelGGL(vsn_mfma, dim3(MTOT / 64), dim3(512), 0, stream,
                     in_, w1, b1v, b2v, bgv, gma, bta, W2p, Wgp, sel_ws, out_sel);
}

// Round 6
// 440.187 us; speedup vs baseline: 1.3729x; 1.1614x over previous
//
#include <hip/hip_runtime.h>
#include <math.h>

// VariableSelectionNetwork — round 8.
// R6 (counted vmcnt) and R7 (depth-2) both ~= R4 => staging latency is NOT the
// bottleneck. Cycle accounting: MFMA 159K cyc/CU (18%), VALU 217K, LDS pipe
// ~180-230K incl. ln_reduce's 128 ds_swizzle shuffles/thread/f with 120-cyc
// dependent chains. Fixes (on the R4 346us base, schedule untouched):
//  * ln_reduce via DPP v_add (quad_perm 0xB1/0x4E, half-mirror 0x141,
//    mirror 0x140): LDS-pipe shuffles -> VALU, ~10x lower reduce latency.
//  * v_cvt_pk_bf16_f32 (RNE, = our f2bf) for all bf16 pair packing.
//  * store_x2_pair lane-pair exchange via DPP mov (xor1) instead of shfl.
//  * ctx sel-dot 4-way parallel (from R6).

#define H 512
#define NF 4
#define MTOT 32768

typedef unsigned short u16;
typedef unsigned int u32;
typedef __attribute__((ext_vector_type(8))) short short8;   // 8 bf16 = 4 VGPRs
typedef __attribute__((ext_vector_type(4))) float f32x4;    // MFMA C/D
typedef __attribute__((ext_vector_type(4))) u32 u32x4;      // packed bf16 x8

__device__ __forceinline__ u16 f2bf(float x) {
  union { float f; u32 u; } v; v.f = x;
  return (u16)((v.u + 0x7fffu + ((v.u >> 16) & 1u)) >> 16);  // RNE
}
__device__ __forceinline__ float bf2f(u32 h16) {
  union { u32 u; float f; } v; v.u = h16 << 16;
  return v.f;
}
__device__ __forceinline__ float elu_f(float x) {
  return x > 0.0f ? x : (__expf(x) - 1.0f);
}
__device__ __forceinline__ float sigmoid_f(float x) {
  return __builtin_amdgcn_rcpf(1.0f + __expf(-x));
}
// packed 2x bf16 (lo->[15:0], hi->[31:16]), RNE — matches f2bf
__device__ __forceinline__ u32 cvtpk(float lo, float hi) {
  u32 r;
  asm("v_cvt_pk_bf16_f32 %0, %1, %2" : "=v"(r) : "v"(lo), "v"(hi));
  return r;
}
// butterfly-add over 16-lane groups via DPP (VALU pipe, no LDS)
template <int CTRL>
__device__ __forceinline__ float dppadd(float v) {
  int t = __builtin_amdgcn_update_dpp(0, __float_as_int(v), CTRL, 0xF, 0xF, true);
  return v + __int_as_float(t);
}
__device__ __forceinline__ float red16(float v) {
  v = dppadd<0xB1>(v);    // xor1 (quad_perm [1,0,3,2])
  v = dppadd<0x4E>(v);    // xor2 (quad_perm [2,3,0,1])
  v = dppadd<0x141>(v);   // row_half_mirror: adds other quad within 8
  v = dppadd<0x140>(v);   // row_mirror: adds other 8-group within 16
  return v;
}

// async global->LDS, 16B per lane; LDS dest = wave-uniform base + lane*16.
__device__ __forceinline__ void glld16(const void* g, void* l) {
  __builtin_amdgcn_global_load_lds(
      (const __attribute__((address_space(1))) u32*)(unsigned long long)(uintptr_t)g,
      (__attribute__((address_space(3))) u32*)(u32)(uintptr_t)l, 16, 0, 0);
}

#define MFMA16(a, b, c) __builtin_amdgcn_mfma_f32_16x16x32_bf16((a), (b), (c), 0, 0, 0)

// ---------------- pack_weights: fp32 -> bf16 B-fragment-major ----------------
// Packed per matrix: (((kk*32 + ntg)*64 + lane)*8 + j); chunk kk = 32k x 512n
// = 32KB contiguous. mats 0-3 W2[f], 4-7 Wg[f], 8 W1c, 9 W2c, 10 Wgc.
__global__ __launch_bounds__(256)
void pack_weights(const float* __restrict__ W2, const float* __restrict__ Wg,
                  const float* __restrict__ W1c, const float* __restrict__ W2c,
                  const float* __restrict__ Wgc,
                  u16* __restrict__ W2p, u16* __restrict__ Wgp, u16* __restrict__ Cp) {
  int g = blockIdx.x * 256 + threadIdx.x;       // 0 .. 11*32768-1
  int r = g & 32767; int mat = g >> 15;
  if (mat >= 11) return;
  int lane = r & 63, nt = (r >> 6) & 31, kk = (r >> 11) & 15;
  const float* src; u16* dst;
  if (mat < 4)      { src = W2 + (size_t)mat * 262144;       dst = W2p + (size_t)mat * 262144; }
  else if (mat < 8) { src = Wg + (size_t)(mat - 4) * 262144; dst = Wgp + (size_t)(mat - 4) * 262144; }
  else              { src = (mat == 8 ? W1c : (mat == 9 ? W2c : Wgc));
                      dst = Cp + (size_t)(mat - 8) * 262144; }
  dst += (((size_t)kk * 32 + nt) * 64 + lane) * 8;
  int n  = nt * 16 + (lane & 15);
  int k0 = kk * 32 + (lane >> 4) * 8;
  short8 pk;
  #pragma unroll
  for (int j = 0; j < 8; ++j) pk[j] = (short)f2bf(src[(size_t)(k0 + j) * H + n]);
  *(short8*)dst = pk;
}

struct TileCtx {
  int tid, wid, lane, quad, col;
};

// ======================= 16-wave machinery (ctx_mfma) =======================
// Block: 1024 thr = 16 waves. M-tile 64 rows. Wave wid owns cols wid*32..+31
// (nt=2 of 16). Per-thread frags: mt=4, nt=2. sA: 64KB bf16 [m][k] XOR-swizzled
// (16B groups, grp = (k>>3) ^ (m&7)). sB: 2 x 32KB chunk buffers (BK=32).

template <bool PREFETCH_TAIL>
__device__ __forceinline__ void gemm_kloop(const TileCtx& c, const u16* Wp,
                                           const u16* nextWp,
                                           u16* sA, u16* sB0, u16* sB1,
                                           f32x4 acc[4][2]) {
  #pragma unroll 1
  for (int kk = 0; kk < 16; ++kk) {
    if (kk < 15) {
      const u16* src = Wp + (kk + 1) * 16384 + c.tid * 8;
      u16* dst = (((kk + 1) & 1) ? sB1 : sB0) + c.tid * 8;
      glld16(src, dst);
      glld16(src + 8192, dst + 8192);
    } else if (PREFETCH_TAIL) {
      const u16* src = nextWp + c.tid * 8;
      glld16(src, sB0 + c.tid * 8);
      glld16(src + 8192, sB0 + c.tid * 8 + 8192);
    }
    const u16* bp = ((kk & 1) ? sB1 : sB0) + c.wid * 1024 + c.lane * 8;
    short8 bb0 = *(const short8*)(bp);
    short8 bb1 = *(const short8*)(bp + 512);
    const int kq = kk * 4 + c.quad;
    const int s0 = (kq ^ (c.col & 7)) * 8;
    short8 a0 = *(const short8*)&sA[(     c.col) * 512 + s0];
    short8 a1 = *(const short8*)&sA[(16 + c.col) * 512 + s0];
    short8 a2 = *(const short8*)&sA[(32 + c.col) * 512 + s0];
    short8 a3 = *(const short8*)&sA[(48 + c.col) * 512 + s0];
    acc[0][0] = MFMA16(a0, bb0, acc[0][0]); acc[0][1] = MFMA16(a0, bb1, acc[0][1]);
    acc[1][0] = MFMA16(a1, bb0, acc[1][0]); acc[1][1] = MFMA16(a1, bb1, acc[1][1]);
    acc[2][0] = MFMA16(a2, bb0, acc[2][0]); acc[2][1] = MFMA16(a2, bb1, acc[2][1]);
    acc[3][0] = MFMA16(a3, bb0, acc[3][0]); acc[3][1] = MFMA16(a3, bb1, acc[3][1]);
    __syncthreads();
  }
}

__device__ __forceinline__ void store_x2_pair(const TileCtx& c, u16* sA,
                                              int mt, int nt, u32 o01, u32 o23) {
  const bool even = (c.lane & 1) == 0;
  const u32 send = even ? o23 : o01;
  const u32 recv = (u32)__builtin_amdgcn_update_dpp(0, (int)send, 0xB1, 0xF, 0xF, true);
  const u32 hi = even ? recv : o23;
  const u32 lo = even ? o01 : recv;
  const u32 dlo = __builtin_amdgcn_perm(hi, lo, 0x05040100u);
  const u32 dhi = __builtin_amdgcn_perm(hi, lo, 0x07060302u);
  const int n  = c.wid * 32 + nt * 16 + c.col;
  const int np = n & ~1;
  const int mA = mt * 16 + c.quad * 4 + (even ? 0 : 2);
  const int iA = mA * 512 + ((((np >> 3) ^ (mA & 7)) << 3) + (np & 7));
  const int mB = mA + 1;
  const int iB = mB * 512 + ((((np >> 3) ^ (mB & 7)) << 3) + (np & 7));
  *(u32*)&sA[iA] = dlo;
  *(u32*)&sA[iB] = dhi;
}

__device__ __forceinline__ void ln_reduce(const TileCtx& c, float* sRedF,
                                          f32x4 acc[4][2]) {
  #pragma unroll
  for (int mt = 0; mt < 4; ++mt) {
    float rs[4], rq[4];
    #pragma unroll
    for (int reg = 0; reg < 4; ++reg) {
      rs[reg] = 0.f; rq[reg] = 0.f;
      #pragma unroll
      for (int nt = 0; nt < 2; ++nt) {
        const float gt = acc[mt][nt][reg];
        rs[reg] += gt; rq[reg] += gt * gt;
      }
      rs[reg] = red16(rs[reg]);
      rq[reg] = red16(rq[reg]);
    }
    if (c.col == 0) {
      #pragma unroll
      for (int reg = 0; reg < 4; ++reg) {
        const int m = mt * 16 + c.quad * 4 + reg;
        float2 sq; sq.x = rs[reg]; sq.y = rq[reg];
        *(float2*)&sRedF[m * 36 + c.wid * 2] = sq;
      }
    }
  }
  __syncthreads();
  if (c.tid < 64) {
    const int row = c.tid;
    float s = 0.f, q = 0.f;
    #pragma unroll
    for (int jj = 0; jj < 8; ++jj) {
      float4 v = *(float4*)&sRedF[row * 36 + jj * 4];
      s += v.x + v.z; q += v.y + v.w;
    }
    const float mu = s * (1.0f / H);
    const float rstd = rsqrtf(q * (1.0f / H) - mu * mu + 1e-3f);
    float2 mr; mr.x = mu; mr.y = rstd;
    *(float2*)&sRedF[2304 + row * 2] = mr;
  }
  __syncthreads();
}

// ---------------- ctx GRN as MFMA: 4 blocks x 64 batch rows ----------------
__global__ __launch_bounds__(1024)
void ctx_mfma(const float* __restrict__ in,       // [B, 512] flat
              const u16* __restrict__ Cp,         // W1cp | W2cp | Wgcp
              const float* __restrict__ b1c, const float* __restrict__ b2c,
              const float* __restrict__ bgc,
              const float* __restrict__ gamma_c, const float* __restrict__ beta_c,
              const float* __restrict__ Wsel, const float* __restrict__ bsel,
              float* __restrict__ sel_ws,         // [B, F]
              float* __restrict__ selw_out)       // [B, T, 1, F]
{
  __shared__ __align__(16) u16 smem[65536];
  u16* const sA  = smem;
  u16* const sB0 = smem + 32768;
  u16* const sB1 = smem + 49152;
  float* const sRedF = (float*)smem;       // LN partials overlay sA (x lives in regs)
  float* const sZ   = (float*)sB0;         // [256][4] logit partials (4KB)
  float* const sSel = (float*)sB0 + 1024;  // [64][4] softmax

  TileCtx c;
  c.tid = threadIdx.x; c.wid = c.tid >> 6; c.lane = c.tid & 63;
  c.quad = c.lane >> 4; c.col = c.lane & 15;
  const int b0 = blockIdx.x * 64;
  const u16* W1cp = Cp;
  const u16* W2cp = Cp + 262144;
  const u16* Wgcp = Cp + 524288;

  // stage W1c chunk0
  glld16(W1cp + c.tid * 8, sB0 + c.tid * 8);
  glld16(W1cp + c.tid * 8 + 8192, sB0 + c.tid * 8 + 8192);

  // A0: flat -> sA bf16 (rotated k-group order to spread LDS write banks)
  {
    const int m = c.tid >> 4;
    const int kb = (c.tid & 15) * 32;
    const float* rowp = in + (size_t)(b0 + m) * H;
    #pragma unroll
    for (int gg = 0; gg < 4; ++gg) {
      const int ge = (gg + (c.tid & 15)) & 3;
      const int k = kb + ge * 8;
      float4 v0 = *(const float4*)&rowp[k];
      float4 v1 = *(const float4*)&rowp[k + 4];
      u32x4 pk4;
      pk4.x = cvtpk(v0.x, v0.y);
      pk4.y = cvtpk(v0.z, v0.w);
      pk4.z = cvtpk(v1.x, v1.y);
      pk4.w = cvtpk(v1.z, v1.w);
      const int grp = (k >> 3) ^ (m & 7);
      *(u32x4*)&sA[m * 512 + grp * 8] = pk4;
    }
  }
  __syncthreads();

  f32x4 acc[4][2];
  #pragma unroll
  for (int mt = 0; mt < 4; ++mt) { acc[mt][0] = (f32x4){0,0,0,0}; acc[mt][1] = (f32x4){0,0,0,0}; }

  // GEMM1: x1 = elu(flat@W1c + b1c) -> sA
  gemm_kloop<true>(c, W1cp, W2cp, sA, sB0, sB1, acc);
  {
    float bv[2] = { b1c[c.wid * 32 + c.col], b1c[c.wid * 32 + 16 + c.col] };
    #pragma unroll
    for (int mt = 0; mt < 4; ++mt)
      #pragma unroll
      for (int nt = 0; nt < 2; ++nt) {
        const u32 o01 = cvtpk(elu_f(acc[mt][nt][0] + bv[nt]), elu_f(acc[mt][nt][1] + bv[nt]));
        const u32 o23 = cvtpk(elu_f(acc[mt][nt][2] + bv[nt]), elu_f(acc[mt][nt][3] + bv[nt]));
        store_x2_pair(c, sA, mt, nt, o01, o23);
      }
  }
  __syncthreads();

  // GEMM2: x = x1@W2c + b2c (keep fp32 in regs, also -> sA)
  float xr[4][2][4];
  #pragma unroll
  for (int mt = 0; mt < 4; ++mt) { acc[mt][0] = (f32x4){0,0,0,0}; acc[mt][1] = (f32x4){0,0,0,0}; }
  gemm_kloop<true>(c, W2cp, Wgcp, sA, sB0, sB1, acc);
  {
    float bv[2] = { b2c[c.wid * 32 + c.col], b2c[c.wid * 32 + 16 + c.col] };
    #pragma unroll
    for (int mt = 0; mt < 4; ++mt)
      #pragma unroll
      for (int nt = 0; nt < 2; ++nt) {
        #pragma unroll
        for (int reg = 0; reg < 4; ++reg) xr[mt][nt][reg] = acc[mt][nt][reg] + bv[nt];
        const u32 o01 = cvtpk(xr[mt][nt][0], xr[mt][nt][1]);
        const u32 o23 = cvtpk(xr[mt][nt][2], xr[mt][nt][3]);
        store_x2_pair(c, sA, mt, nt, o01, o23);
      }
  }
  __syncthreads();

  // GEMM3: gpre = x@Wgc; gate + skip + LN -> ctx
  #pragma unroll
  for (int mt = 0; mt < 4; ++mt) { acc[mt][0] = (f32x4){0,0,0,0}; acc[mt][1] = (f32x4){0,0,0,0}; }
  gemm_kloop<false>(c, Wgcp, nullptr, sA, sB0, sB1, acc);
  {
    float bv[2] = { bgc[c.wid * 32 + c.col], bgc[c.wid * 32 + 16 + c.col] };
    #pragma unroll
    for (int mt = 0; mt < 4; ++mt)
      #pragma unroll
      for (int nt = 0; nt < 2; ++nt) {
        const int n = c.wid * 32 + nt * 16 + c.col;
        #pragma unroll
        for (int reg = 0; reg < 4; ++reg) {
          const int m = mt * 16 + c.quad * 4 + reg;
          const float fl = in[(size_t)(b0 + m) * H + n];
          const float gv = sigmoid_f(acc[mt][nt][reg] + bv[nt]);
          acc[mt][nt][reg] = gv * xr[mt][nt][reg] + (1.0f - gv) * fl;
        }
      }
  }
  ln_reduce(c, sRedF, acc);   // overlays sA; sA re-written below after LN
  // ctx -> sA (plain [m][n] bf16 layout) for the sel dot
  {
    float gm[2], bt[2];
    #pragma unroll
    for (int nt = 0; nt < 2; ++nt) {
      const int n = c.wid * 32 + nt * 16 + c.col;
      gm[nt] = gamma_c[n]; bt[nt] = beta_c[n];
    }
    u16 cv[4][2][4];
    #pragma unroll
    for (int mt = 0; mt < 4; ++mt)
      #pragma unroll
      for (int reg = 0; reg < 4; ++reg) {
        const int m = mt * 16 + c.quad * 4 + reg;
        float2 mr = *(float2*)&sRedF[2304 + m * 2];
        #pragma unroll
        for (int nt = 0; nt < 2; ++nt)
          cv[mt][nt][reg] = f2bf(gm[nt] * ((acc[mt][nt][reg] - mr.x) * mr.y) + bt[nt]);
      }
    __syncthreads();   // sRedF reads done; sA region reusable
    #pragma unroll
    for (int mt = 0; mt < 4; ++mt)
      #pragma unroll
      for (int reg = 0; reg < 4; ++reg) {
        const int m = mt * 16 + c.quad * 4 + reg;
        #pragma unroll
        for (int nt = 0; nt < 2; ++nt)
          sA[m * 512 + c.wid * 32 + nt * 16 + c.col] = cv[mt][nt][reg];
      }
  }
  __syncthreads();

  // sel logits: all 1024 threads, (row, f, quarter): each dots 128 h
  {
    const int r = c.tid >> 4, fq = (c.tid >> 2) & 3, p = c.tid & 3;
    float z = 0.f;
    const u16* rowp = &sA[r * 512 + p * 128];
    const float* wp = Wsel + (size_t)p * 128 * NF + fq;
    #pragma unroll 8
    for (int h = 0; h < 128; ++h) z += bf2f(rowp[h]) * wp[h * NF];
    sZ[((r * 4 + fq) << 2) + p] = z;
  }
  __syncthreads();
  if (c.tid < 64) {
    const int r = c.tid;
    float zz[4];
    #pragma unroll
    for (int ff = 0; ff < 4; ++ff) {
      float4 v = *(float4*)&sZ[(r * 4 + ff) << 2];
      zz[ff] = v.x + v.y + v.z + v.w + bsel[ff];
    }
    float mx = fmaxf(fmaxf(zz[0], zz[1]), fmaxf(zz[2], zz[3]));
    float e0 = __expf(zz[0]-mx), e1 = __expf(zz[1]-mx), e2 = __expf(zz[2]-mx), e3 = __expf(zz[3]-mx);
    float inv = __builtin_amdgcn_rcpf(e0 + e1 + e2 + e3);
    sSel[r*4]   = e0*inv; sSel[r*4+1] = e1*inv;
    sSel[r*4+2] = e2*inv; sSel[r*4+3] = e3*inv;
  }
  __syncthreads();
  if (c.tid < 256) {
    const int r = c.tid >> 2, f = c.tid & 3;
    sel_ws[(b0 + r) * NF + f] = sSel[r * 4 + f];
  }
  {
    const int m = c.tid >> 4;
    const int jb = (c.tid & 15) * 32;
    float s0 = sSel[m*4], s1 = sSel[m*4+1], s2 = sSel[m*4+2], s3 = sSel[m*4+3];
    float4 v; v.x = s0; v.y = s1; v.z = s2; v.w = s3;
    #pragma unroll
    for (int j = 0; j < 8; ++j)
      *(float4*)&selw_out[(size_t)(b0 + m) * H + jb + j * 4] = v;
  }
}

// ======================= 8-wave machinery (vsn_mfma) =======================
// Block: 512 thr = 8 waves. M-tile 64 rows. Wave wid owns cols wid*64..+63
// (nt=4 of 16). Per-thread frags: mt=4, nt=4 -> 16 MFMA per 8 ds_read_b128.

__device__ __forceinline__ void stage_chunk8(int tid, const u16* src, u16* dst) {
  glld16(src + tid * 8,         dst + tid * 8);
  glld16(src + tid * 8 + 4096,  dst + tid * 8 + 4096);
  glld16(src + tid * 8 + 8192,  dst + tid * 8 + 8192);
  glld16(src + tid * 8 + 12288, dst + tid * 8 + 12288);
}

template <bool PREFETCH_TAIL>
__device__ __forceinline__ void gemm_kloop8(const TileCtx& c, const u16* Wp,
                                            const u16* nextWp,
                                            u16* sA, u16* sB0, u16* sB1,
                                            f32x4 acc[4][4]) {
  #pragma unroll 1
  for (int kk = 0; kk < 16; ++kk) {
    if (kk < 15) {
      stage_chunk8(c.tid, Wp + (kk + 1) * 16384, (((kk + 1) & 1) ? sB1 : sB0));
    } else if (PREFETCH_TAIL) {
      stage_chunk8(c.tid, nextWp, sB0);
    }
    const u16* bp = ((kk & 1) ? sB1 : sB0) + c.wid * 2048 + c.lane * 8;
    short8 bb[4];
    #pragma unroll
    for (int nt = 0; nt < 4; ++nt) bb[nt] = *(const short8*)(bp + nt * 512);
    const int kq = kk * 4 + c.quad;
    const int s0 = (kq ^ (c.col & 7)) * 8;
    #pragma unroll
    for (int mt = 0; mt < 4; ++mt) {
      short8 a = *(const short8*)&sA[(mt * 16 + c.col) * 512 + s0];
      #pragma unroll
      for (int nt = 0; nt < 4; ++nt)
        acc[mt][nt] = MFMA16(a, bb[nt], acc[mt][nt]);
    }
    __syncthreads();
  }
}

// store one C-layout value-pair set into sA[m][k] bf16 via lane-pair exchange.
__device__ __forceinline__ void store_x2_pair_n(const TileCtx& c, u16* sA,
                                                int mt, int n, u32 o01, u32 o23) {
  const bool even = (c.lane & 1) == 0;
  const u32 send = even ? o23 : o01;
  const u32 recv = (u32)__builtin_amdgcn_update_dpp(0, (int)send, 0xB1, 0xF, 0xF, true);
  const u32 hi = even ? recv : o23;
  const u32 lo = even ? o01 : recv;
  const u32 dlo = __builtin_amdgcn_perm(hi, lo, 0x05040100u);
  const u32 dhi = __builtin_amdgcn_perm(hi, lo, 0x07060302u);
  const int np = n & ~1;
  const int mA = mt * 16 + c.quad * 4 + (even ? 0 : 2);
  const int iA = mA * 512 + ((((np >> 3) ^ (mA & 7)) << 3) + (np & 7));
  const int mB = mA + 1;
  const int iB = mB * 512 + ((((np >> 3) ^ (mB & 7)) << 3) + (np & 7));
  *(u32*)&sA[iA] = dlo;
  *(u32*)&sA[iB] = dhi;
}

// LN over 512 cols for 64 rows, 8-wave version. Partials stride 20 floats.
__device__ __forceinline__ void ln_reduce8(const TileCtx& c, float* sRedF,
                                           f32x4 acc[4][4]) {
  #pragma unroll
  for (int mt = 0; mt < 4; ++mt) {
    float rs[4], rq[4];
    #pragma unroll
    for (int reg = 0; reg < 4; ++reg) {
      rs[reg] = 0.f; rq[reg] = 0.f;
      #pragma unroll
      for (int nt = 0; nt < 4; ++nt) {
        const float gt = acc[mt][nt][reg];
        rs[reg] += gt; rq[reg] += gt * gt;
      }
      rs[reg] = red16(rs[reg]);
      rq[reg] = red16(rq[reg]);
    }
    if (c.col == 0) {
      #pragma unroll
      for (int reg = 0; reg < 4; ++reg) {
        const int m = mt * 16 + c.quad * 4 + reg;
        float2 sq; sq.x = rs[reg]; sq.y = rq[reg];
        *(float2*)&sRedF[m * 20 + c.wid * 2] = sq;
      }
    }
  }
  __syncthreads();
  if (c.tid < 64) {
    const int row = c.tid;
    float s = 0.f, q = 0.f;
    #pragma unroll
    for (int jj = 0; jj < 4; ++jj) {
      float4 v = *(float4*)&sRedF[row * 20 + jj * 4];
      s += v.x + v.z; q += v.y + v.w;
    }
    const float mu = s * (1.0f / H);
    const float rstd = rsqrtf(q * (1.0f / H) - mu * mu + 1e-3f);
    float2 mr; mr.x = mu; mr.y = rstd;
    *(float2*)&sRedF[1280 + row * 2] = mr;
  }
  __syncthreads();
}

// ---------------- vsn_mfma: per-variable GRNs + weighted selection ----------------
__global__ __launch_bounds__(512, 2)
void vsn_mfma(const float* __restrict__ in,     // [MTOT, F]
              const float* __restrict__ w1, const float* __restrict__ b1,
              const float* __restrict__ b2, const float* __restrict__ bg,
              const float* __restrict__ gamma, const float* __restrict__ beta,
              const u16* __restrict__ W2p, const u16* __restrict__ Wgp,
              const float* __restrict__ sel_ws,  // [B, F]
              float* __restrict__ out)           // [MTOT, H]
{
  __shared__ __align__(16) u16 smem[65536];
  u16* const sA  = smem;              // [64][512] bf16 XOR-swizzled, 64 KB
  u16* const sB0 = smem + 32768;      // 32 KB chunk
  u16* const sB1 = smem + 49152;      // 32 KB chunk
  float* const sRedF = (float*)smem;  // LN partials overlay sA (x2 in regs)

  TileCtx c;
  c.tid = threadIdx.x; c.wid = c.tid >> 6; c.lane = c.tid & 63;
  c.quad = c.lane >> 4; c.col = c.lane & 15;
  const int row0 = blockIdx.x * 64;
  const int bidx = row0 >> 7;

  f32x4 outacc[4][4];
  #pragma unroll
  for (int mt = 0; mt < 4; ++mt)
    #pragma unroll
    for (int nt = 0; nt < 4; ++nt) outacc[mt][nt] = (f32x4){0,0,0,0};

  // stage f=0 GEMM1 chunk0 (overlapped by first A1 phase)
  stage_chunk8(c.tid, W2p, sB0);

  #pragma unroll 1
  for (int f = 0; f < NF; ++f) {
    const u16* W2f = W2p + (size_t)f * 262144;
    const u16* Wgf = Wgp + (size_t)f * 262144;
    const u16* W2n = W2p + (size_t)((f + 1) & 3) * 262144;  // next f's GEMM1 (wraps, harmless)

    // A1: sA[m][k] = bf16(elu(v[m]*w1[k] + b1[k])), rotated k-group order
    {
      const int m  = c.tid >> 3;
      const int kb = (c.tid & 7) * 64;
      const float v = in[(size_t)(row0 + m) * NF + f];
      const float* w1f = w1 + f * H;
      const float* b1f = b1 + f * H;
      #pragma unroll
      for (int gg = 0; gg < 8; ++gg) {
        const int ge = (gg + (c.tid & 7)) & 7;
        const int k = kb + ge * 8;
        float4 wv0 = *(const float4*)&w1f[k];
        float4 wv1 = *(const float4*)&w1f[k + 4];
        float4 bv0 = *(const float4*)&b1f[k];
        float4 bv1 = *(const float4*)&b1f[k + 4];
        u32x4 pk4;
        pk4.x = cvtpk(elu_f(fmaf(v, wv0.x, bv0.x)), elu_f(fmaf(v, wv0.y, bv0.y)));
        pk4.y = cvtpk(elu_f(fmaf(v, wv0.z, bv0.z)), elu_f(fmaf(v, wv0.w, bv0.w)));
        pk4.z = cvtpk(elu_f(fmaf(v, wv1.x, bv1.x)), elu_f(fmaf(v, wv1.y, bv1.y)));
        pk4.w = cvtpk(elu_f(fmaf(v, wv1.z, bv1.z)), elu_f(fmaf(v, wv1.w, bv1.w)));
        const int grp = (k >> 3) ^ (m & 7);
        *(u32x4*)&sA[m * 512 + grp * 8] = pk4;
      }
    }
    __syncthreads();

    f32x4 acc[4][4];
    #pragma unroll
    for (int mt = 0; mt < 4; ++mt)
      #pragma unroll
      for (int nt = 0; nt < 4; ++nt) acc[mt][nt] = (f32x4){0,0,0,0};

    // GEMM1 (tail-prefetches Wgf chunk0 into sB0)
    gemm_kloop8<true>(c, W2f, Wgf, sA, sB0, sB1, acc);

    // epilogue1: x2 = acc + b2 -> packed regs + sA
    u32 x2p[4][4][2];
    {
      float bv[4];
      #pragma unroll
      for (int nt = 0; nt < 4; ++nt) bv[nt] = b2[f * H + c.wid * 64 + nt * 16 + c.col];
      #pragma unroll
      for (int mt = 0; mt < 4; ++mt)
        #pragma unroll
        for (int nt = 0; nt < 4; ++nt) {
          const u32 o01 = cvtpk(acc[mt][nt][0] + bv[nt], acc[mt][nt][1] + bv[nt]);
          const u32 o23 = cvtpk(acc[mt][nt][2] + bv[nt], acc[mt][nt][3] + bv[nt]);
          x2p[mt][nt][0] = o01; x2p[mt][nt][1] = o23;
          store_x2_pair_n(c, sA, mt, c.wid * 64 + nt * 16 + c.col, o01, o23);
        }
    }
    __syncthreads();

    // GEMM2 (tail-prefetches next f's W2 chunk0 -> overlaps gate+LN epilogue)
    #pragma unroll
    for (int mt = 0; mt < 4; ++mt)
      #pragma unroll
      for (int nt = 0; nt < 4; ++nt) acc[mt][nt] = (f32x4){0,0,0,0};
    gemm_kloop8<true>(c, Wgf, W2n, sA, sB0, sB1, acc);

    // gate + LN + weighted accumulate
    {
      const float selw = sel_ws[bidx * NF + f];
      float bv[4];
      #pragma unroll
      for (int nt = 0; nt < 4; ++nt) bv[nt] = bg[f * H + c.wid * 64 + nt * 16 + c.col];
      #pragma unroll
      for (int mt = 0; mt < 4; ++mt) {
        float vr[4];
        #pragma unroll
        for (int reg = 0; reg < 4; ++reg)
          vr[reg] = in[(size_t)(row0 + mt * 16 + c.quad * 4 + reg) * NF + f];
        #pragma unroll
        for (int nt = 0; nt < 4; ++nt)
          #pragma unroll
          for (int reg = 0; reg < 4; ++reg) {
            const u32 w = x2p[mt][nt][reg >> 1];
            const float x2v = bf2f((reg & 1) ? (w >> 16) : (w & 0xffffu));
            const float gv = sigmoid_f(acc[mt][nt][reg] + bv[nt]);
            acc[mt][nt][reg] = gv * x2v + (1.0f - gv) * vr[reg];
          }
      }
      ln_reduce8(c, sRedF, acc);
      float gm[4], bt[4];
      #pragma unroll
      for (int nt = 0; nt < 4; ++nt) {
        const int n = f * H + c.wid * 64 + nt * 16 + c.col;
        gm[nt] = gamma[n]; bt[nt] = beta[n];
      }
      #pragma unroll
      for (int mt = 0; mt < 4; ++mt)
        #pragma unroll
        for (int reg = 0; reg < 4; ++reg) {
          const int m = mt * 16 + c.quad * 4 + reg;
          float2 mr = *(float2*)&sRedF[1280 + m * 2];
          #pragma unroll
          for (int nt = 0; nt < 4; ++nt) {
            const float tv = gm[nt] * ((acc[mt][nt][reg] - mr.x) * mr.y) + bt[nt];
            outacc[mt][nt][reg] = fmaf(selw, tv, outacc[mt][nt][reg]);
          }
        }
      __syncthreads();   // sRedF reads done before next f's A1 overwrites sA
    }
  }

  // store selected [MTOT, H]
  #pragma unroll
  for (int mt = 0; mt < 4; ++mt)
    #pragma unroll
    for (int reg = 0; reg < 4; ++reg) {
      const int m = row0 + mt * 16 + c.quad * 4 + reg;
      #pragma unroll
      for (int nt = 0; nt < 4; ++nt)
        out[(size_t)m * H + c.wid * 64 + nt * 16 + c.col] = outacc[mt][nt][reg];
    }
}

extern "C" void kernel_launch(void* const* d_in, const int* in_sizes, int n_in,
                              void* d_out, int out_size, void* d_ws, size_t ws_size,
                              hipStream_t stream) {
  const float* in_     = (const float*)d_in[0];
  const float* W1c     = (const float*)d_in[1];
  const float* b1c     = (const float*)d_in[2];
  const float* W2c     = (const float*)d_in[3];
  const float* b2c     = (const float*)d_in[4];
  const float* Wgc     = (const float*)d_in[5];
  const float* bgc     = (const float*)d_in[6];
  const float* gamma_c = (const float*)d_in[7];
  const float* beta_c  = (const float*)d_in[8];
  const float* Wsel    = (const float*)d_in[9];
  const float* bsel    = (const float*)d_in[10];
  const float* w1      = (const float*)d_in[11];
  const float* b1v     = (const float*)d_in[12];
  const float* W2      = (const float*)d_in[13];
  const float* b2v     = (const float*)d_in[14];
  const float* Wg      = (const float*)d_in[15];
  const float* bgv     = (const float*)d_in[16];
  const float* gma     = (const float*)d_in[17];
  const float* bta     = (const float*)d_in[18];

  float* out_sel = (float*)d_out;                      // [MTOT, H]
  float* out_w   = (float*)d_out + (size_t)MTOT * H;   // [B, T, 1, F]

  float* sel_ws = (float*)d_ws;                        // 4 KB
  u16*   W2p    = (u16*)((char*)d_ws + 4096);          // 2 MB
  u16*   Wgp    = W2p + (size_t)NF * H * H;            // 2 MB
  u16*   Cp     = Wgp + (size_t)NF * H * H;            // 1.5 MB (W1c|W2c|Wgc)

  hipLaunchKernelGGL(pack_weights, dim3(1408), dim3(256), 0, stream,
                     W2, Wg, W1c, W2c, Wgc, W2p, Wgp, Cp);
  hipLaunchKernelGGL(ctx_mfma, dim3(4), dim3(1024), 0, stream,
                     in_, Cp, b1c, b2c, bgc, gamma_c, beta_c,
                     Wsel, bsel, sel_ws, out_w);
  hipLaunchKernelGGL(vsn_mfma, dim3(MTOT / 64), dim3(512), 0, stream,
                     in_, w1, b1v, b2v, bgv, gma, bta, W2p, Wgp, sel_ws, out_sel);
}

// Round 7
// 427.425 us; speedup vs baseline: 1.4139x; 1.0299x over previous
//
#include <hip/hip_runtime.h>
#include <math.h>

// VariableSelectionNetwork — round 9.
// R8 banked vsn at 288us (DPP LN + cvtpk). Ledger: total 440 - vsn 288 =
// ~150us is ctx_mfma (4 blocks = 4/256 CUs, reg-capped 1024-thr kernel) +
// pack, fully serialized in-stream. Fix: widen the ctx path.
//  * ctx_g1/g2: 64m x 64n slab GEMMs, grid 32 (4m x 8n), 256 thr, K=512 in
//    4KB chunks; intermediates x1/x as bf16 in ws. Slab-packed W1c/W2c.
//  * ctx_g3: GEMM3+gate+LN+softmax+selw on the proven vsn kloop8 (512 thr,
//    grid 4); ctx stays in regs, sel partials via DPP red16.
//  * vsn_mfma / kloop8 byte-identical to R8.

#define H 512
#define NF 4
#define MTOT 32768

typedef unsigned short u16;
typedef unsigned int u32;
typedef __attribute__((ext_vector_type(8))) short short8;   // 8 bf16 = 4 VGPRs
typedef __attribute__((ext_vector_type(4))) float f32x4;    // MFMA C/D
typedef __attribute__((ext_vector_type(4))) u32 u32x4;      // packed bf16 x8

__device__ __forceinline__ u16 f2bf(float x) {
  union { float f; u32 u; } v; v.f = x;
  return (u16)((v.u + 0x7fffu + ((v.u >> 16) & 1u)) >> 16);  // RNE
}
__device__ __forceinline__ float bf2f(u32 h16) {
  union { u32 u; float f; } v; v.u = h16 << 16;
  return v.f;
}
__device__ __forceinline__ float elu_f(float x) {
  return x > 0.0f ? x : (__expf(x) - 1.0f);
}
__device__ __forceinline__ float sigmoid_f(float x) {
  return __builtin_amdgcn_rcpf(1.0f + __expf(-x));
}
// packed 2x bf16 (lo->[15:0], hi->[31:16]), RNE — matches f2bf
__device__ __forceinline__ u32 cvtpk(float lo, float hi) {
  u32 r;
  asm("v_cvt_pk_bf16_f32 %0, %1, %2" : "=v"(r) : "v"(lo), "v"(hi));
  return r;
}
// butterfly-add over 16-lane groups via DPP (VALU pipe, no LDS)
template <int CTRL>
__device__ __forceinline__ float dppadd(float v) {
  int t = __builtin_amdgcn_update_dpp(0, __float_as_int(v), CTRL, 0xF, 0xF, true);
  return v + __int_as_float(t);
}
__device__ __forceinline__ float red16(float v) {
  v = dppadd<0xB1>(v);    // xor1
  v = dppadd<0x4E>(v);    // xor2
  v = dppadd<0x141>(v);   // row_half_mirror
  v = dppadd<0x140>(v);   // row_mirror
  return v;
}

// async global->LDS, 16B per lane; LDS dest = wave-uniform base + lane*16.
__device__ __forceinline__ void glld16(const void* g, void* l) {
  __builtin_amdgcn_global_load_lds(
      (const __attribute__((address_space(1))) u32*)(unsigned long long)(uintptr_t)g,
      (__attribute__((address_space(3))) u32*)(u32)(uintptr_t)l, 16, 0, 0);
}

#define MFMA16(a, b, c) __builtin_amdgcn_mfma_f32_16x16x32_bf16((a), (b), (c), 0, 0, 0)

// x value stored in swizzled sA at logical (m,n):
__device__ __forceinline__ int sA_idx(int m, int n) {
  return m * 512 + ((((n >> 3) ^ (m & 7)) << 3) + (n & 7));
}

struct TileCtx {
  int tid, wid, lane, quad, col;
};

// ---------------- pack_vsn: fp32 -> bf16 B-fragment-major (old chunk layout)
// chunk kk = 32k x 512n = 32KB. mats 0-3 W2[f], 4-7 Wg[f]. grid 1024.
__global__ __launch_bounds__(256)
void pack_vsn(const float* __restrict__ W2, const float* __restrict__ Wg,
              u16* __restrict__ W2p, u16* __restrict__ Wgp) {
  int g = blockIdx.x * 256 + threadIdx.x;       // 0 .. 8*32768-1
  int r = g & 32767; int mat = g >> 15;
  int lane = r & 63, nt = (r >> 6) & 31, kk = (r >> 11) & 15;
  const float* src; u16* dst;
  if (mat < 4) { src = W2 + (size_t)mat * 262144;       dst = W2p + (size_t)mat * 262144; }
  else         { src = Wg + (size_t)(mat - 4) * 262144; dst = Wgp + (size_t)(mat - 4) * 262144; }
  dst += (size_t)r * 8;
  int n  = nt * 16 + (lane & 15);
  int k0 = kk * 32 + (lane >> 4) * 8;
  short8 pk;
  #pragma unroll
  for (int j = 0; j < 8; ++j) pk[j] = (short)f2bf(src[(size_t)(k0 + j) * H + n]);
  *(short8*)dst = pk;
}

// ---------------- pack_ctx: W1c/W2c slab layout + Wgc old chunk layout.
// slab: r = nb*4096 + kk*256 + ntg*64 + lane; n = nb*64+ntg*16+(lane&15);
// k0 = kk*32+(lane>>4)*8. grid 384.
__global__ __launch_bounds__(256)
void pack_ctx(const float* __restrict__ W1c, const float* __restrict__ W2c,
              const float* __restrict__ Wgc, u16* __restrict__ Cp) {
  int g = blockIdx.x * 256 + threadIdx.x;       // 0 .. 3*32768-1
  int r = g & 32767; int mat = g >> 15;
  const float* src = (mat == 0) ? W1c : (mat == 1) ? W2c : Wgc;
  u16* dst = Cp + (size_t)mat * 262144 + (size_t)r * 8;
  int lane = r & 63;
  int n, k0;
  if (mat < 2) {        // slab layout
    int nb = r >> 12, kk = (r >> 8) & 15, ntg = (r >> 6) & 3;
    n  = nb * 64 + ntg * 16 + (lane & 15);
    k0 = kk * 32 + (lane >> 4) * 8;
  } else {              // old chunk layout (for kloop8)
    int nt = (r >> 6) & 31, kk = (r >> 11) & 15;
    n  = nt * 16 + (lane & 15);
    k0 = kk * 32 + (lane >> 4) * 8;
  }
  short8 pk;
  #pragma unroll
  for (int j = 0; j < 8; ++j) pk[j] = (short)f2bf(src[(size_t)(k0 + j) * H + n]);
  *(short8*)dst = pk;
}

// ======================= 4-wave slab GEMM (ctx_g1/g2) =======================
// Block 256 thr = 4 waves; tile 64m x 64n, K=512. Wave wid owns cols
// wid*16..+15. Per-thread: mt=4, nt=1 -> 4 MFMA per 5 ds_read_b128.
// sA 64KB swizzled; sB 2 x 4KB chunk (32k x 64n).

__device__ __forceinline__ void slab_kloop(const TileCtx& c, const u16* Wslab,
                                           u16* sA, u16* sB0, u16* sB1,
                                           f32x4 acc[4]) {
  #pragma unroll 1
  for (int kk = 0; kk < 16; ++kk) {
    if (kk < 15)
      glld16(Wslab + (kk + 1) * 2048 + c.tid * 8,
             (((kk + 1) & 1) ? sB1 : sB0) + c.tid * 8);
    const u16* bp = ((kk & 1) ? sB1 : sB0) + c.wid * 512 + c.lane * 8;
    short8 bb = *(const short8*)(bp);
    const int kq = kk * 4 + c.quad;
    const int s0 = (kq ^ (c.col & 7)) * 8;
    short8 a0 = *(const short8*)&sA[(     c.col) * 512 + s0];
    short8 a1 = *(const short8*)&sA[(16 + c.col) * 512 + s0];
    short8 a2 = *(const short8*)&sA[(32 + c.col) * 512 + s0];
    short8 a3 = *(const short8*)&sA[(48 + c.col) * 512 + s0];
    acc[0] = MFMA16(a0, bb, acc[0]);
    acc[1] = MFMA16(a1, bb, acc[1]);
    acc[2] = MFMA16(a2, bb, acc[2]);
    acc[3] = MFMA16(a3, bb, acc[3]);
    __syncthreads();
  }
}

// g1: x1 = elu(flat @ W1c + b1c) -> bf16 x1g. grid 32 = mb*8+nb.
__global__ __launch_bounds__(256)
void ctx_g1(const float* __restrict__ in, const u16* __restrict__ Cp,
            const float* __restrict__ b1c, u16* __restrict__ x1g) {
  __shared__ __align__(16) u16 smem[36864];     // 64KB sA + 2x4KB sB
  u16* const sA  = smem;
  u16* const sB0 = smem + 32768;
  u16* const sB1 = smem + 34816;
  TileCtx c;
  c.tid = threadIdx.x; c.wid = c.tid >> 6; c.lane = c.tid & 63;
  c.quad = c.lane >> 4; c.col = c.lane & 15;
  const int mb = blockIdx.x >> 3, nb = blockIdx.x & 7;
  const int m0 = mb * 64;
  const u16* Wslab = Cp + (size_t)nb * 32768;   // W1c slab

  glld16(Wslab + c.tid * 8, sB0 + c.tid * 8);   // chunk0

  // A-fill: flat fp32 -> bf16 swizzled sA
  {
    const int m = c.tid >> 2;
    const int kb = (c.tid & 3) * 128;
    const float* rowp = in + (size_t)(m0 + m) * H;
    #pragma unroll
    for (int gg = 0; gg < 16; ++gg) {
      const int ge = (gg + (c.tid & 3) * 4) & 15;
      const int k = kb + ge * 8;
      float4 v0 = *(const float4*)&rowp[k];
      float4 v1 = *(const float4*)&rowp[k + 4];
      u32x4 pk4;
      pk4.x = cvtpk(v0.x, v0.y); pk4.y = cvtpk(v0.z, v0.w);
      pk4.z = cvtpk(v1.x, v1.y); pk4.w = cvtpk(v1.z, v1.w);
      const int grp = (k >> 3) ^ (m & 7);
      *(u32x4*)&sA[m * 512 + grp * 8] = pk4;
    }
  }
  __syncthreads();

  f32x4 acc[4];
  #pragma unroll
  for (int mt = 0; mt < 4; ++mt) acc[mt] = (f32x4){0,0,0,0};
  slab_kloop(c, Wslab, sA, sB0, sB1, acc);

  const int n = nb * 64 + c.wid * 16 + c.col;
  const float bv = b1c[n];
  #pragma unroll
  for (int mt = 0; mt < 4; ++mt)
    #pragma unroll
    for (int reg = 0; reg < 4; ++reg) {
      const int m = m0 + mt * 16 + c.quad * 4 + reg;
      x1g[(size_t)m * H + n] = f2bf(elu_f(acc[mt][reg] + bv));
    }
}

// g2: x = x1 @ W2c + b2c -> bf16 xg. grid 32.
__global__ __launch_bounds__(256)
void ctx_g2(const u16* __restrict__ x1g, const u16* __restrict__ Cp,
            const float* __restrict__ b2c, u16* __restrict__ xg) {
  __shared__ __align__(16) u16 smem[36864];
  u16* const sA  = smem;
  u16* const sB0 = smem + 32768;
  u16* const sB1 = smem + 34816;
  TileCtx c;
  c.tid = threadIdx.x; c.wid = c.tid >> 6; c.lane = c.tid & 63;
  c.quad = c.lane >> 4; c.col = c.lane & 15;
  const int mb = blockIdx.x >> 3, nb = blockIdx.x & 7;
  const int m0 = mb * 64;
  const u16* Wslab = Cp + 262144 + (size_t)nb * 32768;   // W2c slab

  glld16(Wslab + c.tid * 8, sB0 + c.tid * 8);

  // A-fill: x1 bf16 -> swizzled sA
  {
    const int m = c.tid >> 2;
    const int kb = (c.tid & 3) * 128;
    const u16* rowp = x1g + (size_t)(m0 + m) * H;
    #pragma unroll
    for (int gg = 0; gg < 16; ++gg) {
      const int ge = (gg + (c.tid & 3) * 4) & 15;
      const int k = kb + ge * 8;
      short8 w = *(const short8*)&rowp[k];
      const int grp = (k >> 3) ^ (m & 7);
      *(short8*)&sA[m * 512 + grp * 8] = w;
    }
  }
  __syncthreads();

  f32x4 acc[4];
  #pragma unroll
  for (int mt = 0; mt < 4; ++mt) acc[mt] = (f32x4){0,0,0,0};
  slab_kloop(c, Wslab, sA, sB0, sB1, acc);

  const int n = nb * 64 + c.wid * 16 + c.col;
  const float bv = b2c[n];
  #pragma unroll
  for (int mt = 0; mt < 4; ++mt)
    #pragma unroll
    for (int reg = 0; reg < 4; ++reg) {
      const int m = m0 + mt * 16 + c.quad * 4 + reg;
      xg[(size_t)m * H + n] = f2bf(acc[mt][reg] + bv);
    }
}

// ======================= 8-wave machinery (kloop8, shared) =======================

__device__ __forceinline__ void stage_chunk8(int tid, const u16* src, u16* dst) {
  glld16(src + tid * 8,         dst + tid * 8);
  glld16(src + tid * 8 + 4096,  dst + tid * 8 + 4096);
  glld16(src + tid * 8 + 8192,  dst + tid * 8 + 8192);
  glld16(src + tid * 8 + 12288, dst + tid * 8 + 12288);
}

template <bool PREFETCH_TAIL>
__device__ __forceinline__ void gemm_kloop8(const TileCtx& c, const u16* Wp,
                                            const u16* nextWp,
                                            u16* sA, u16* sB0, u16* sB1,
                                            f32x4 acc[4][4]) {
  #pragma unroll 1
  for (int kk = 0; kk < 16; ++kk) {
    if (kk < 15) {
      stage_chunk8(c.tid, Wp + (kk + 1) * 16384, (((kk + 1) & 1) ? sB1 : sB0));
    } else if (PREFETCH_TAIL) {
      stage_chunk8(c.tid, nextWp, sB0);
    }
    const u16* bp = ((kk & 1) ? sB1 : sB0) + c.wid * 2048 + c.lane * 8;
    short8 bb[4];
    #pragma unroll
    for (int nt = 0; nt < 4; ++nt) bb[nt] = *(const short8*)(bp + nt * 512);
    const int kq = kk * 4 + c.quad;
    const int s0 = (kq ^ (c.col & 7)) * 8;
    #pragma unroll
    for (int mt = 0; mt < 4; ++mt) {
      short8 a = *(const short8*)&sA[(mt * 16 + c.col) * 512 + s0];
      #pragma unroll
      for (int nt = 0; nt < 4; ++nt)
        acc[mt][nt] = MFMA16(a, bb[nt], acc[mt][nt]);
    }
    __syncthreads();
  }
}

__device__ __forceinline__ void store_x2_pair_n(const TileCtx& c, u16* sA,
                                                int mt, int n, u32 o01, u32 o23) {
  const bool even = (c.lane & 1) == 0;
  const u32 send = even ? o23 : o01;
  const u32 recv = (u32)__builtin_amdgcn_update_dpp(0, (int)send, 0xB1, 0xF, 0xF, true);
  const u32 hi = even ? recv : o23;
  const u32 lo = even ? o01 : recv;
  const u32 dlo = __builtin_amdgcn_perm(hi, lo, 0x05040100u);
  const u32 dhi = __builtin_amdgcn_perm(hi, lo, 0x07060302u);
  const int np = n & ~1;
  const int mA = mt * 16 + c.quad * 4 + (even ? 0 : 2);
  const int iA = mA * 512 + ((((np >> 3) ^ (mA & 7)) << 3) + (np & 7));
  const int mB = mA + 1;
  const int iB = mB * 512 + ((((np >> 3) ^ (mB & 7)) << 3) + (np & 7));
  *(u32*)&sA[iA] = dlo;
  *(u32*)&sA[iB] = dhi;
}

// LN over 512 cols for 64 rows, 8-wave. Partials stride 20 floats.
__device__ __forceinline__ void ln_reduce8(const TileCtx& c, float* sRedF,
                                           f32x4 acc[4][4]) {
  #pragma unroll
  for (int mt = 0; mt < 4; ++mt) {
    float rs[4], rq[4];
    #pragma unroll
    for (int reg = 0; reg < 4; ++reg) {
      rs[reg] = 0.f; rq[reg] = 0.f;
      #pragma unroll
      for (int nt = 0; nt < 4; ++nt) {
        const float gt = acc[mt][nt][reg];
        rs[reg] += gt; rq[reg] += gt * gt;
      }
      rs[reg] = red16(rs[reg]);
      rq[reg] = red16(rq[reg]);
    }
    if (c.col == 0) {
      #pragma unroll
      for (int reg = 0; reg < 4; ++reg) {
        const int m = mt * 16 + c.quad * 4 + reg;
        float2 sq; sq.x = rs[reg]; sq.y = rq[reg];
        *(float2*)&sRedF[m * 20 + c.wid * 2] = sq;
      }
    }
  }
  __syncthreads();
  if (c.tid < 64) {
    const int row = c.tid;
    float s = 0.f, q = 0.f;
    #pragma unroll
    for (int jj = 0; jj < 4; ++jj) {
      float4 v = *(float4*)&sRedF[row * 20 + jj * 4];
      s += v.x + v.z; q += v.y + v.w;
    }
    const float mu = s * (1.0f / H);
    const float rstd = rsqrtf(q * (1.0f / H) - mu * mu + 1e-3f);
    float2 mr; mr.x = mu; mr.y = rstd;
    *(float2*)&sRedF[1280 + row * 2] = mr;
  }
  __syncthreads();
}

// g3: gpre = x @ Wgc; gate + LN -> ctx (regs); sel softmax; selw_out. grid 4.
__global__ __launch_bounds__(512)
void ctx_g3(const float* __restrict__ in, const u16* __restrict__ xg,
            const u16* __restrict__ Cp,
            const float* __restrict__ bgc,
            const float* __restrict__ gamma_c, const float* __restrict__ beta_c,
            const float* __restrict__ Wsel, const float* __restrict__ bsel,
            float* __restrict__ sel_ws,         // [B, F]
            float* __restrict__ selw_out)       // [B, T, 1, F]
{
  __shared__ __align__(16) u16 smem[65536];
  u16* const sA  = smem;
  u16* const sB0 = smem + 32768;
  u16* const sB1 = smem + 49152;
  float* const sRedF = (float*)sB0;          // LN partials (sB free after kloop)
  float* const sZp   = (float*)sB0 + 2048;   // [64][8][4] sel partials
  float* const sZf   = (float*)sB0 + 4096;   // [64][4] logits
  float* const sSel  = (float*)sB0 + 4352;   // [64][4] softmax

  TileCtx c;
  c.tid = threadIdx.x; c.wid = c.tid >> 6; c.lane = c.tid & 63;
  c.quad = c.lane >> 4; c.col = c.lane & 15;
  const int b0 = blockIdx.x * 64;
  const u16* Wgcp = Cp + 524288;   // old chunk layout

  stage_chunk8(c.tid, Wgcp, sB0);  // chunk0

  // A-fill: x bf16 -> swizzled sA
  {
    const int m  = c.tid >> 3;
    const int kb = (c.tid & 7) * 64;
    const u16* rowp = xg + (size_t)(b0 + m) * H;
    #pragma unroll
    for (int gg = 0; gg < 8; ++gg) {
      const int ge = (gg + (c.tid & 7)) & 7;
      const int k = kb + ge * 8;
      short8 w = *(const short8*)&rowp[k];
      const int grp = (k >> 3) ^ (m & 7);
      *(short8*)&sA[m * 512 + grp * 8] = w;
    }
  }
  __syncthreads();

  f32x4 acc[4][4];
  #pragma unroll
  for (int mt = 0; mt < 4; ++mt)
    #pragma unroll
    for (int nt = 0; nt < 4; ++nt) acc[mt][nt] = (f32x4){0,0,0,0};
  gemm_kloop8<false>(c, Wgcp, nullptr, sA, sB0, sB1, acc);

  // gate: x from sA, skip from in (fp32)
  {
    float bv[4];
    #pragma unroll
    for (int nt = 0; nt < 4; ++nt) bv[nt] = bgc[c.wid * 64 + nt * 16 + c.col];
    #pragma unroll
    for (int mt = 0; mt < 4; ++mt)
      #pragma unroll
      for (int nt = 0; nt < 4; ++nt) {
        const int n = c.wid * 64 + nt * 16 + c.col;
        #pragma unroll
        for (int reg = 0; reg < 4; ++reg) {
          const int m = mt * 16 + c.quad * 4 + reg;
          const float xv = bf2f(sA[sA_idx(m, n)]);
          const float fl = in[(size_t)(b0 + m) * H + n];
          const float gv = sigmoid_f(acc[mt][nt][reg] + bv[nt]);
          acc[mt][nt][reg] = gv * xv + (1.0f - gv) * fl;
        }
      }
  }
  __syncthreads();              // all sA/acc gate reads done; sB reusable
  ln_reduce8(c, sRedF, acc);

  // ctx (regs) + sel partials: zp[f] = sum_n ctx[m,n]*Wsel[n,f]
  {
    float gm[4], bt[4]; float4 ws4[4];
    #pragma unroll
    for (int nt = 0; nt < 4; ++nt) {
      const int n = c.wid * 64 + nt * 16 + c.col;
      gm[nt] = gamma_c[n]; bt[nt] = beta_c[n];
      ws4[nt] = *(const float4*)&Wsel[n * NF];
    }
    #pragma unroll
    for (int mt = 0; mt < 4; ++mt)
      #pragma unroll
      for (int reg = 0; reg < 4; ++reg) {
        const int m = mt * 16 + c.quad * 4 + reg;
        float2 mr = *(float2*)&sRedF[1280 + m * 2];
        float zp[4] = {0.f, 0.f, 0.f, 0.f};
        #pragma unroll
        for (int nt = 0; nt < 4; ++nt) {
          const float ctxv = gm[nt] * ((acc[mt][nt][reg] - mr.x) * mr.y) + bt[nt];
          zp[0] = fmaf(ctxv, ws4[nt].x, zp[0]);
          zp[1] = fmaf(ctxv, ws4[nt].y, zp[1]);
          zp[2] = fmaf(ctxv, ws4[nt].z, zp[2]);
          zp[3] = fmaf(ctxv, ws4[nt].w, zp[3]);
        }
        #pragma unroll
        for (int f = 0; f < 4; ++f) zp[f] = red16(zp[f]);
        if (c.col == 0) {
          #pragma unroll
          for (int f = 0; f < 4; ++f) sZp[(m * 8 + c.wid) * 4 + f] = zp[f];
        }
      }
  }
  __syncthreads();
  if (c.tid < 256) {
    const int m = c.tid >> 2, f = c.tid & 3;
    float z = bsel[f];
    #pragma unroll
    for (int w = 0; w < 8; ++w) z += sZp[(m * 8 + w) * 4 + f];
    sZf[m * 4 + f] = z;
  }
  __syncthreads();
  if (c.tid < 64) {
    const int m = c.tid;
    float z0 = sZf[m*4], z1 = sZf[m*4+1], z2 = sZf[m*4+2], z3 = sZf[m*4+3];
    float mx = fmaxf(fmaxf(z0, z1), fmaxf(z2, z3));
    float e0 = __expf(z0-mx), e1 = __expf(z1-mx), e2 = __expf(z2-mx), e3 = __expf(z3-mx);
    float inv = __builtin_amdgcn_rcpf(e0 + e1 + e2 + e3);
    sSel[m*4]   = e0*inv; sSel[m*4+1] = e1*inv;
    sSel[m*4+2] = e2*inv; sSel[m*4+3] = e3*inv;
    sel_ws[(b0+m)*NF]   = e0*inv; sel_ws[(b0+m)*NF+1] = e1*inv;
    sel_ws[(b0+m)*NF+2] = e2*inv; sel_ws[(b0+m)*NF+3] = e3*inv;
  }
  __syncthreads();
  {
    const int m = c.tid >> 3;
    const int jb = (c.tid & 7) * 64;
    float4 v; v.x = sSel[m*4]; v.y = sSel[m*4+1]; v.z = sSel[m*4+2]; v.w = sSel[m*4+3];
    #pragma unroll
    for (int j = 0; j < 16; ++j)
      *(float4*)&selw_out[(size_t)(b0 + m) * H + jb + j * 4] = v;
  }
}

// ---------------- vsn_mfma: per-variable GRNs + weighted selection ----------------
__global__ __launch_bounds__(512, 2)
void vsn_mfma(const float* __restrict__ in,     // [MTOT, F]
              const float* __restrict__ w1, const float* __restrict__ b1,
              const float* __restrict__ b2, const float* __restrict__ bg,
              const float* __restrict__ gamma, const float* __restrict__ beta,
              const u16* __restrict__ W2p, const u16* __restrict__ Wgp,
              const float* __restrict__ sel_ws,  // [B, F]
              float* __restrict__ out)           // [MTOT, H]
{
  __shared__ __align__(16) u16 smem[65536];
  u16* const sA  = smem;              // [64][512] bf16 XOR-swizzled, 64 KB
  u16* const sB0 = smem + 32768;      // 32 KB chunk
  u16* const sB1 = smem + 49152;      // 32 KB chunk
  float* const sRedF = (float*)smem;  // LN partials overlay sA (x2 in regs)

  TileCtx c;
  c.tid = threadIdx.x; c.wid = c.tid >> 6; c.lane = c.tid & 63;
  c.quad = c.lane >> 4; c.col = c.lane & 15;
  const int row0 = blockIdx.x * 64;
  const int bidx = row0 >> 7;

  f32x4 outacc[4][4];
  #pragma unroll
  for (int mt = 0; mt < 4; ++mt)
    #pragma unroll
    for (int nt = 0; nt < 4; ++nt) outacc[mt][nt] = (f32x4){0,0,0,0};

  // stage f=0 GEMM1 chunk0 (overlapped by first A1 phase)
  stage_chunk8(c.tid, W2p, sB0);

  #pragma unroll 1
  for (int f = 0; f < NF; ++f) {
    const u16* W2f = W2p + (size_t)f * 262144;
    const u16* Wgf = Wgp + (size_t)f * 262144;
    const u16* W2n = W2p + (size_t)((f + 1) & 3) * 262144;  // next f's GEMM1 (wraps, harmless)

    // A1: sA[m][k] = bf16(elu(v[m]*w1[k] + b1[k])), rotated k-group order
    {
      const int m  = c.tid >> 3;
      const int kb = (c.tid & 7) * 64;
      const float v = in[(size_t)(row0 + m) * NF + f];
      const float* w1f = w1 + f * H;
      const float* b1f = b1 + f * H;
      #pragma unroll
      for (int gg = 0; gg < 8; ++gg) {
        const int ge = (gg + (c.tid & 7)) & 7;
        const int k = kb + ge * 8;
        float4 wv0 = *(const float4*)&w1f[k];
        float4 wv1 = *(const float4*)&w1f[k + 4];
        float4 bv0 = *(const float4*)&b1f[k];
        float4 bv1 = *(const float4*)&b1f[k + 4];
        u32x4 pk4;
        pk4.x = cvtpk(elu_f(fmaf(v, wv0.x, bv0.x)), elu_f(fmaf(v, wv0.y, bv0.y)));
        pk4.y = cvtpk(elu_f(fmaf(v, wv0.z, bv0.z)), elu_f(fmaf(v, wv0.w, bv0.w)));
        pk4.z = cvtpk(elu_f(fmaf(v, wv1.x, bv1.x)), elu_f(fmaf(v, wv1.y, bv1.y)));
        pk4.w = cvtpk(elu_f(fmaf(v, wv1.z, bv1.z)), elu_f(fmaf(v, wv1.w, bv1.w)));
        const int grp = (k >> 3) ^ (m & 7);
        *(u32x4*)&sA[m * 512 + grp * 8] = pk4;
      }
    }
    __syncthreads();

    f32x4 acc[4][4];
    #pragma unroll
    for (int mt = 0; mt < 4; ++mt)
      #pragma unroll
      for (int nt = 0; nt < 4; ++nt) acc[mt][nt] = (f32x4){0,0,0,0};

    // GEMM1 (tail-prefetches Wgf chunk0 into sB0)
    gemm_kloop8<true>(c, W2f, Wgf, sA, sB0, sB1, acc);

    // epilogue1: x2 = acc + b2 -> packed regs + sA
    u32 x2p[4][4][2];
    {
      float bv[4];
      #pragma unroll
      for (int nt = 0; nt < 4; ++nt) bv[nt] = b2[f * H + c.wid * 64 + nt * 16 + c.col];
      #pragma unroll
      for (int mt = 0; mt < 4; ++mt)
        #pragma unroll
        for (int nt = 0; nt < 4; ++nt) {
          const u32 o01 = cvtpk(acc[mt][nt][0] + bv[nt], acc[mt][nt][1] + bv[nt]);
          const u32 o23 = cvtpk(acc[mt][nt][2] + bv[nt], acc[mt][nt][3] + bv[nt]);
          x2p[mt][nt][0] = o01; x2p[mt][nt][1] = o23;
          store_x2_pair_n(c, sA, mt, c.wid * 64 + nt * 16 + c.col, o01, o23);
        }
    }
    __syncthreads();

    // GEMM2 (tail-prefetches next f's W2 chunk0 -> overlaps gate+LN epilogue)
    #pragma unroll
    for (int mt = 0; mt < 4; ++mt)
      #pragma unroll
      for (int nt = 0; nt < 4; ++nt) acc[mt][nt] = (f32x4){0,0,0,0};
    gemm_kloop8<true>(c, Wgf, W2n, sA, sB0, sB1, acc);

    // gate + LN + weighted accumulate
    {
      const float selw = sel_ws[bidx * NF + f];
      float bv[4];
      #pragma unroll
      for (int nt = 0; nt < 4; ++nt) bv[nt] = bg[f * H + c.wid * 64 + nt * 16 + c.col];
      #pragma unroll
      for (int mt = 0; mt < 4; ++mt) {
        float vr[4];
        #pragma unroll
        for (int reg = 0; reg < 4; ++reg)
          vr[reg] = in[(size_t)(row0 + mt * 16 + c.quad * 4 + reg) * NF + f];
        #pragma unroll
        for (int nt = 0; nt < 4; ++nt)
          #pragma unroll
          for (int reg = 0; reg < 4; ++reg) {
            const u32 w = x2p[mt][nt][reg >> 1];
            const float x2v = bf2f((reg & 1) ? (w >> 16) : (w & 0xffffu));
            const float gv = sigmoid_f(acc[mt][nt][reg] + bv[nt]);
            acc[mt][nt][reg] = gv * x2v + (1.0f - gv) * vr[reg];
          }
      }
      ln_reduce8(c, sRedF, acc);
      float gm[4], bt[4];
      #pragma unroll
      for (int nt = 0; nt < 4; ++nt) {
        const int n = f * H + c.wid * 64 + nt * 16 + c.col;
        gm[nt] = gamma[n]; bt[nt] = beta[n];
      }
      #pragma unroll
      for (int mt = 0; mt < 4; ++mt)
        #pragma unroll
        for (int reg = 0; reg < 4; ++reg) {
          const int m = mt * 16 + c.quad * 4 + reg;
          float2 mr = *(float2*)&sRedF[1280 + m * 2];
          #pragma unroll
          for (int nt = 0; nt < 4; ++nt) {
            const float tv = gm[nt] * ((acc[mt][nt][reg] - mr.x) * mr.y) + bt[nt];
            outacc[mt][nt][reg] = fmaf(selw, tv, outacc[mt][nt][reg]);
          }
        }
      __syncthreads();   // sRedF reads done before next f's A1 overwrites sA
    }
  }

  // store selected [MTOT, H]
  #pragma unroll
  for (int mt = 0; mt < 4; ++mt)
    #pragma unroll
    for (int reg = 0; reg < 4; ++reg) {
      const int m = row0 + mt * 16 + c.quad * 4 + reg;
      #pragma unroll
      for (int nt = 0; nt < 4; ++nt)
        out[(size_t)m * H + c.wid * 64 + nt * 16 + c.col] = outacc[mt][nt][reg];
    }
}

extern "C" void kernel_launch(void* const* d_in, const int* in_sizes, int n_in,
                              void* d_out, int out_size, void* d_ws, size_t ws_size,
                              hipStream_t stream) {
  const float* in_     = (const float*)d_in[0];
  const float* W1c     = (const float*)d_in[1];
  const float* b1c     = (const float*)d_in[2];
  const float* W2c     = (const float*)d_in[3];
  const float* b2c     = (const float*)d_in[4];
  const float* Wgc     = (const float*)d_in[5];
  const float* bgc     = (const float*)d_in[6];
  const float* gamma_c = (const float*)d_in[7];
  const float* beta_c  = (const float*)d_in[8];
  const float* Wsel    = (const float*)d_in[9];
  const float* bsel    = (const float*)d_in[10];
  const float* w1      = (const float*)d_in[11];
  const float* b1v     = (const float*)d_in[12];
  const float* W2      = (const float*)d_in[13];
  const float* b2v     = (const float*)d_in[14];
  const float* Wg      = (const float*)d_in[15];
  const float* bgv     = (const float*)d_in[16];
  const float* gma     = (const float*)d_in[17];
  const float* bta     = (const float*)d_in[18];

  float* out_sel = (float*)d_out;                      // [MTOT, H]
  float* out_w   = (float*)d_out + (size_t)MTOT * H;   // [B, T, 1, F]

  float* sel_ws = (float*)d_ws;                        // 4 KB
  u16*   W2p    = (u16*)((char*)d_ws + 4096);          // 2 MB
  u16*   Wgp    = W2p + (size_t)NF * H * H;            // 2 MB
  u16*   Cp     = Wgp + (size_t)NF * H * H;            // 1.5 MB (W1c|W2c|Wgc)
  u16*   x1g    = Cp + 3 * 262144;                     // 256 KB bf16 [256][512]
  u16*   xg     = x1g + 131072;                        // 256 KB bf16 [256][512]

  hipLaunchKernelGGL(pack_ctx, dim3(384), dim3(256), 0, stream,
                     W1c, W2c, Wgc, Cp);
  hipLaunchKernelGGL(pack_vsn, dim3(1024), dim3(256), 0, stream,
                     W2, Wg, W2p, Wgp);
  hipLaunchKernelGGL(ctx_g1, dim3(32), dim3(256), 0, stream,
                     in_, Cp, b1c, x1g);
  hipLaunchKernelGGL(ctx_g2, dim3(32), dim3(256), 0, stream,
                     x1g, Cp, b2c, xg);
  hipLaunchKernelGGL(ctx_g3, dim3(4), dim3(512), 0, stream,
                     in_, xg, Cp, bgc, gamma_c, beta_c, Wsel, bsel,
                     sel_ws, out_w);
  hipLaunchKernelGGL(vsn_mfma, dim3(MTOT / 64), dim3(512), 0, stream,
                     in_, w1, b1v, b2v, bgv, gma, bta, W2p, Wgp, sel_ws, out_sel);
}